// Round 1
// baseline (866.465 us; speedup 1.0000x reference)
//
#include <hip/hip_runtime.h>
#include <math.h>

#define B_ 2
#define T_ 4096
#define S_ 4096
#define NH_ 16
#define MD_ 64
#define FF_ 128
#define H_ 4
#define HD_ 16
#define BT_ (B_*T_)

__device__ __forceinline__ float wsum64(float v) {
  #pragma unroll
  for (int off = 32; off > 0; off >>= 1) v += __shfl_xor(v, off, 64);
  return v;
}
__device__ __forceinline__ float leaky_(float x) { return x >= 0.f ? x : 0.2f * x; }

// ---------------------------------------------------------------------------
// K1: brute-force kNN. One wave per target point. coords_source tile in LDS.
// Each lane scans 64 sources keeping a sorted top-16 of (d2, idx); waves merge
// by repeated lexicographic-min extraction -> exact jax.lax.top_k order
// (ascending d2, ties -> lower index).
// Outputs: xnh[n][i] = x[b][idx], rel[n][i][2] = cs[idx] - ct[n].
// ---------------------------------------------------------------------------
__global__ __launch_bounds__(256) void k1_knn(
    const float* __restrict__ coords_target, const float* __restrict__ coords_source,
    const float* __restrict__ x, float* __restrict__ xnh, float* __restrict__ rel) {
  __shared__ float2 cs_s[S_];
  const int tid = threadIdx.x;
  const int lane = tid & 63;
  const int n = blockIdx.x * 4 + (tid >> 6);   // target id, 4 waves/block
  const int b = n >> 12;                       // T_ = 4096
  const float2* cs = (const float2*)coords_source + (size_t)b * S_;
  for (int i = tid; i < S_; i += 256) cs_s[i] = cs[i];
  __syncthreads();

  const float ctx = coords_target[n*2+0], cty = coords_target[n*2+1];
  float kd[16]; int ki[16];
  #pragma unroll
  for (int j = 0; j < 16; ++j) { kd[j] = INFINITY; ki[j] = 0x7fffffff; }

  for (int kk = 0; kk < 64; ++kk) {
    int s = (kk << 6) | lane;
    float2 c = cs_s[s];
    float dx = ctx - c.x, dy = cty - c.y;
    float d2 = dx*dx + dy*dy;
    if (d2 < kd[15]) {
      float cd = d2; int ci = s;
      #pragma unroll
      for (int j = 0; j < 16; ++j) {
        bool sw = cd < kd[j];
        float td = sw ? kd[j] : cd;  int ti = sw ? ki[j] : ci;
        kd[j]    = sw ? cd : kd[j];  ki[j]    = sw ? ci : ki[j];
        cd = td; ci = ti;
      }
    }
  }

  int myidx = 0;
  for (int r = 0; r < 16; ++r) {
    float hd = kd[0]; int hi = ki[0];
    #pragma unroll
    for (int off = 32; off > 0; off >>= 1) {
      float od = __shfl_xor(hd, off, 64); int oi = __shfl_xor(hi, off, 64);
      bool take = (od < hd) || (od == hd && oi < hi);
      hd = take ? od : hd; hi = take ? oi : hi;
    }
    if (kd[0] == hd && ki[0] == hi) {   // unique winner (idx unique per lane)
      #pragma unroll
      for (int j = 0; j < 15; ++j) { kd[j] = kd[j+1]; ki[j] = ki[j+1]; }
      kd[15] = INFINITY; ki[15] = 0x7fffffff;
    }
    if (lane == r) myidx = hi;
  }

  if (lane < 16) {
    float2 c = cs_s[myidx];
    xnh[(size_t)n*NH_ + lane] = x[(size_t)b*S_ + myidx];
    rel[((size_t)n*NH_ + lane)*2 + 0] = c.x - ctx;
    rel[((size_t)n*NH_ + lane)*2 + 1] = c.y - cty;
  }
}

// ---------------------------------------------------------------------------
// K2: relative-position MLP (2->128->64) + value bias add + LayerNorm(ln1).
// One wave handles 4 rows (lane = output channel). hidden staged in LDS.
// h_out[row][m], row = n*16 + neighbor.
// ---------------------------------------------------------------------------
__global__ __launch_bounds__(256) void k2_pe(
    const float* __restrict__ rel, const float* __restrict__ xnh,
    const float* __restrict__ pe_w1, const float* __restrict__ pe_b1,
    const float* __restrict__ pe_w2, const float* __restrict__ pe_b2,
    const float* __restrict__ ln1_g, const float* __restrict__ ln1_b,
    float* __restrict__ h_out) {
  const int lane = threadIdx.x & 63;
  const int wave = threadIdx.x >> 6;
  __shared__ float hid[4][4][128];
  const int row0 = blockIdx.x * 16 + wave * 4;

  float c0[4], c1[4], xn[4];
  #pragma unroll
  for (int rr = 0; rr < 4; ++rr) {
    int row = row0 + rr;
    float r0 = rel[(size_t)row*2+0], r1 = rel[(size_t)row*2+1];
    float a0 = log1pf(fabsf(r0)), a1 = log1pf(fabsf(r1));
    c0[rr] = r0 > 0.f ? a0 : (r0 < 0.f ? -a0 : 0.f);
    c1[rr] = r1 > 0.f ? a1 : (r1 < 0.f ? -a1 : 0.f);
    xn[rr] = xnh[row];
  }
  // pe_w1 is (2,128): [j] is k=0 row, [128+j] is k=1 row
  const float w1a0 = pe_w1[lane],    w1a1 = pe_w1[128+lane], b1a = pe_b1[lane];
  const float w1b0 = pe_w1[64+lane], w1b1 = pe_w1[192+lane], b1b = pe_b1[64+lane];
  #pragma unroll
  for (int rr = 0; rr < 4; ++rr) {
    hid[wave][rr][lane]    = fmaxf(fmaf(c0[rr], w1a0, fmaf(c1[rr], w1a1, b1a)), 0.f);
    hid[wave][rr][lane+64] = fmaxf(fmaf(c0[rr], w1b0, fmaf(c1[rr], w1b1, b1b)), 0.f);
  }
  __syncthreads();

  const float b2 = pe_b2[lane];
  float acc[4] = {b2, b2, b2, b2};
  for (int j = 0; j < 128; ++j) {
    float w2 = pe_w2[(size_t)j*64 + lane];
    #pragma unroll
    for (int rr = 0; rr < 4; ++rr) acc[rr] = fmaf(hid[wave][rr][j], w2, acc[rr]);
  }

  const float g = ln1_g[lane], bb = ln1_b[lane];
  #pragma unroll
  for (int rr = 0; rr < 4; ++rr) {
    float v = xn[rr] + acc[rr];           // x_nh + pe (broadcast add)
    float mu = wsum64(v) * (1.f/64.f);
    float d = v - mu;
    float var = wsum64(d*d) * (1.f/64.f);
    h_out[(size_t)(row0+rr)*64 + lane] = d * rsqrtf(var + 1e-5f) * g + bb;
  }
}

// ---------------------------------------------------------------------------
// K3: fused q/k projection + cosine attention + (factorized) out-proj + LN2
//     + per-neighborhood MLP + LN3 -> hu. One wave per (b,t).
// Factorization: v[j][m] = x_nh[j]*v_w[m]  =>
//   (att@v)@out_w [i][m] = sum_h svx[i][h]*wvo_h[m],
//   svx[i][h] = sum_j att[i,h,j]*x_nh[j], wvo_h = v_w[h-slice] @ out_w.
// ---------------------------------------------------------------------------
#define QKS 66   // q_s/k_s row stride (pad for banks)
#define HTS 20   // h_t row stride (pad; multiple of 4 for float4)
__global__ __launch_bounds__(256) void k3_attn(
    const float* __restrict__ h_in, const float* __restrict__ xnh,
    const float* __restrict__ q_w, const float* __restrict__ k_w,
    const float* __restrict__ v_w, const float* __restrict__ logit_scale,
    const float* __restrict__ out_w, const float* __restrict__ out_b,
    const float* __restrict__ nh_w1, const float* __restrict__ nh_b1,
    const float* __restrict__ nh_w2, const float* __restrict__ nh_b2,
    const float* __restrict__ ln2_g, const float* __restrict__ ln2_b,
    const float* __restrict__ ln3_g, const float* __restrict__ ln3_b,
    float* __restrict__ hu_out) {
  const int lane = threadIdx.x & 63;
  const int wave = threadIdx.x >> 6;
  const int n = blockIdx.x * 4 + wave;
  __shared__ float h_t[4][64][HTS];    // transposed h: [channel][neighbor]
  __shared__ float q_s[4][16][QKS];
  __shared__ float k_s[4][16][QKS];
  __shared__ float svx_s[4][16][4];

  // 1. load h tile: keep per-lane column in regs, also store transposed
  const float* hb = h_in + (size_t)n * (NH_*MD_);
  float hr[16];
  #pragma unroll
  for (int i = 0; i < 16; ++i) {
    hr[i] = hb[i*64 + lane];
    h_t[wave][lane][i] = hr[i];
  }
  float xv[16];
  #pragma unroll
  for (int i = 0; i < 16; ++i) xv[i] = xnh[(size_t)n*NH_ + i];

  // wvo_h[m=lane] = sum_d v_w[h*16+d] * out_w[(h*16+d)*64 + lane]
  float wvo[4];
  #pragma unroll
  for (int h = 0; h < 4; ++h) {
    float a = 0.f;
    for (int d = 0; d < 16; ++d)
      a = fmaf(v_w[h*16+d], out_w[(size_t)(h*16+d)*64 + lane], a);
    wvo[h] = a;
  }
  __syncthreads();

  // 2. q = h@q_w, k = h@k_w   (lane = output channel m)
  float aq[16], ak[16];
  #pragma unroll
  for (int i = 0; i < 16; ++i) { aq[i] = 0.f; ak[i] = 0.f; }
  for (int c = 0; c < 64; ++c) {
    float qc = q_w[(size_t)c*64 + lane];
    float kc = k_w[(size_t)c*64 + lane];
    #pragma unroll
    for (int i4 = 0; i4 < 4; ++i4) {
      float4 hv = *(const float4*)&h_t[wave][c][i4*4];
      aq[i4*4+0] = fmaf(hv.x, qc, aq[i4*4+0]);
      aq[i4*4+1] = fmaf(hv.y, qc, aq[i4*4+1]);
      aq[i4*4+2] = fmaf(hv.z, qc, aq[i4*4+2]);
      aq[i4*4+3] = fmaf(hv.w, qc, aq[i4*4+3]);
      ak[i4*4+0] = fmaf(hv.x, kc, ak[i4*4+0]);
      ak[i4*4+1] = fmaf(hv.y, kc, ak[i4*4+1]);
      ak[i4*4+2] = fmaf(hv.z, kc, ak[i4*4+2]);
      ak[i4*4+3] = fmaf(hv.w, kc, ak[i4*4+3]);
    }
  }
  #pragma unroll
  for (int i = 0; i < 16; ++i) { q_s[wave][i][lane] = aq[i]; k_s[wave][i][lane] = ak[i]; }
  __syncthreads();

  // 3. attention: lane = (head, row) = (lane>>4, lane&15)
  const int h_id = lane >> 4, i_id = lane & 15;
  float qv[16]; float qs = 0.f;
  #pragma unroll
  for (int d = 0; d < 16; ++d) {
    qv[d] = q_s[wave][i_id][h_id*16+d];
    qs = fmaf(qv[d], qv[d], qs);
  }
  const float rq = 1.f / (sqrtf(qs) + 1e-12f);
  const float sc = expf(fminf(logit_scale[h_id], 4.60517019f)); // log(100)
  float lg[16];
  #pragma unroll
  for (int j = 0; j < 16; ++j) {
    float ks = 0.f, dt = 0.f;
    #pragma unroll
    for (int d = 0; d < 16; ++d) {
      float kv = k_s[wave][j][h_id*16+d];
      ks = fmaf(kv, kv, ks);
      dt = fmaf(qv[d], kv, dt);
    }
    lg[j] = dt * rq * (1.f/(sqrtf(ks)+1e-12f)) * sc;
  }
  float mx = lg[0];
  #pragma unroll
  for (int j = 1; j < 16; ++j) mx = fmaxf(mx, lg[j]);
  float se = 0.f, sx = 0.f;
  #pragma unroll
  for (int j = 0; j < 16; ++j) {
    float e = __expf(lg[j] - mx);
    se += e;
    sx = fmaf(e, xv[j], sx);
  }
  svx_s[wave][i_id][h_id] = sx / se;
  __syncthreads();

  // 4. out projection (factorized) + residual + LN2
  const float ob = out_b[lane], g2 = ln2_g[lane], bb2 = ln2_b[lane];
  float h2[16];
  #pragma unroll
  for (int i = 0; i < 16; ++i) {
    float o = ob;
    #pragma unroll
    for (int h = 0; h < 4; ++h) o = fmaf(svx_s[wave][i][h], wvo[h], o);
    float t = hr[i] + o;
    float mu = wsum64(t) * (1.f/64.f);
    float d = t - mu;
    float var = wsum64(d*d) * (1.f/64.f);
    h2[i] = d * rsqrtf(var + 1e-5f) * g2 + bb2;
  }
  // store h2 transposed for broadcasts
  #pragma unroll
  for (int i = 0; i < 16; ++i) h_t[wave][lane][i] = h2[i];
  __syncthreads();

  // 5. per-neighborhood MLP: 64->128->1, leaky, broadcast residual
  float ha[16], hc[16];
  const float nb1a = nh_b1[lane], nb1b = nh_b1[64+lane];
  #pragma unroll
  for (int i = 0; i < 16; ++i) { ha[i] = nb1a; hc[i] = nb1b; }
  for (int c = 0; c < 64; ++c) {
    float wa = nh_w1[(size_t)c*128 + lane];
    float wb = nh_w1[(size_t)c*128 + 64 + lane];
    #pragma unroll
    for (int i4 = 0; i4 < 4; ++i4) {
      float4 hv = *(const float4*)&h_t[wave][c][i4*4];
      ha[i4*4+0] = fmaf(hv.x, wa, ha[i4*4+0]); hc[i4*4+0] = fmaf(hv.x, wb, hc[i4*4+0]);
      ha[i4*4+1] = fmaf(hv.y, wa, ha[i4*4+1]); hc[i4*4+1] = fmaf(hv.y, wb, hc[i4*4+1]);
      ha[i4*4+2] = fmaf(hv.z, wa, ha[i4*4+2]); hc[i4*4+2] = fmaf(hv.z, wb, hc[i4*4+2]);
      ha[i4*4+3] = fmaf(hv.w, wa, ha[i4*4+3]); hc[i4*4+3] = fmaf(hv.w, wb, hc[i4*4+3]);
    }
  }
  const float w2a = nh_w2[lane], w2b = nh_w2[64+lane], nb2 = nh_b2[0];
  float h3[16]; float s1 = 0.f, s2 = 0.f;
  #pragma unroll
  for (int i = 0; i < 16; ++i) {
    float pa = fmaf(leaky_(ha[i]), w2a, leaky_(hc[i]) * w2b);
    float sm = wsum64(pa);
    float mi = leaky_(sm + nb2);
    float v3 = h2[i] + mi;
    h3[i] = v3; s1 += v3; s2 = fmaf(v3, v3, s2);
  }

  // 6. LN3 over all 1024 channels of this (b,t) + write hu
  s1 = wsum64(s1); s2 = wsum64(s2);
  float mu = s1 * (1.f/1024.f);
  float var = s2 * (1.f/1024.f) - mu*mu;
  float rs = rsqrtf(var + 1e-5f);
  float* hu = hu_out + (size_t)n * 1024;
  #pragma unroll
  for (int i = 0; i < 16; ++i) {
    int cch = i*64 + lane;
    hu[cch] = (h3[i] - mu) * rs * ln3_g[cch] + ln3_b[cch];
  }
}

// ---------------------------------------------------------------------------
// K4/K5: C = leaky(A @ W + bias). A: Mx1024 (M=8192), W: 1024x1024 row-major.
// 128x128 block tile, BK=8, 256 threads, 8x8 microtile, fp32.
// ---------------------------------------------------------------------------
__global__ __launch_bounds__(256) void k4_gemm(
    const float* __restrict__ A, const float* __restrict__ W,
    const float* __restrict__ bias, float* __restrict__ C) {
  __shared__ float As[8][128];
  __shared__ float Bs[8][128];
  const int tid = threadIdx.x;
  const int tx = tid & 15, ty = tid >> 4;
  const int row0 = blockIdx.x * 128, col0 = blockIdx.y * 128;
  const int arow = tid >> 1, ak4 = (tid & 1) * 4;
  const int brow = tid >> 5, bcol4 = (tid & 31) * 4;
  const float* Ap = A + (size_t)(row0 + arow) * 1024 + ak4;
  const float* Wp = W + (size_t)brow * 1024 + col0 + bcol4;

  float acc[8][8];
  #pragma unroll
  for (int i = 0; i < 8; ++i)
    #pragma unroll
    for (int j = 0; j < 8; ++j) acc[i][j] = 0.f;

  for (int k0 = 0; k0 < 1024; k0 += 8) {
    float4 av = *(const float4*)(Ap + k0);
    float4 bv = *(const float4*)(Wp + (size_t)k0 * 1024);
    __syncthreads();
    As[ak4+0][arow] = av.x; As[ak4+1][arow] = av.y;
    As[ak4+2][arow] = av.z; As[ak4+3][arow] = av.w;
    *(float4*)&Bs[brow][bcol4] = bv;
    __syncthreads();
    #pragma unroll
    for (int kk = 0; kk < 8; ++kk) {
      float af[8], bf[8];
      *(float4*)&af[0] = *(const float4*)&As[kk][ty*8];
      *(float4*)&af[4] = *(const float4*)&As[kk][ty*8+4];
      *(float4*)&bf[0] = *(const float4*)&Bs[kk][tx*8];
      *(float4*)&bf[4] = *(const float4*)&Bs[kk][tx*8+4];
      #pragma unroll
      for (int i = 0; i < 8; ++i)
        #pragma unroll
        for (int j = 0; j < 8; ++j) acc[i][j] = fmaf(af[i], bf[j], acc[i][j]);
    }
  }

  float bvs[8];
  #pragma unroll
  for (int j = 0; j < 8; ++j) bvs[j] = bias[col0 + tx*8 + j];
  #pragma unroll
  for (int i = 0; i < 8; ++i) {
    float* cp = C + (size_t)(row0 + ty*8 + i) * 1024 + col0 + tx*8;
    float4 v0, v1;
    v0.x = leaky_(acc[i][0] + bvs[0]); v0.y = leaky_(acc[i][1] + bvs[1]);
    v0.z = leaky_(acc[i][2] + bvs[2]); v0.w = leaky_(acc[i][3] + bvs[3]);
    v1.x = leaky_(acc[i][4] + bvs[4]); v1.y = leaky_(acc[i][5] + bvs[5]);
    v1.z = leaky_(acc[i][6] + bvs[6]); v1.w = leaky_(acc[i][7] + bvs[7]);
    *(float4*)cp = v0; *(float4*)(cp + 4) = v1;
  }
}

// ---------------------------------------------------------------------------
extern "C" void kernel_launch(void* const* d_in, const int* in_sizes, int n_in,
                              void* d_out, int out_size, void* d_ws, size_t ws_size,
                              hipStream_t stream) {
  (void)in_sizes; (void)n_in; (void)out_size; (void)ws_size;
  const float* x     = (const float*)d_in[0];
  const float* ct    = (const float*)d_in[1];
  const float* cs    = (const float*)d_in[2];
  const float* pe_w1 = (const float*)d_in[3];
  const float* pe_b1 = (const float*)d_in[4];
  const float* pe_w2 = (const float*)d_in[5];
  const float* pe_b2 = (const float*)d_in[6];
  const float* q_w   = (const float*)d_in[7];
  const float* k_w   = (const float*)d_in[8];
  const float* v_w   = (const float*)d_in[9];
  const float* lsc   = (const float*)d_in[10];
  const float* out_w = (const float*)d_in[11];
  const float* out_b = (const float*)d_in[12];
  const float* nh_w1 = (const float*)d_in[13];
  const float* nh_b1 = (const float*)d_in[14];
  const float* nh_w2 = (const float*)d_in[15];
  const float* nh_b2 = (const float*)d_in[16];
  const float* uf_w1 = (const float*)d_in[17];
  const float* uf_b1 = (const float*)d_in[18];
  const float* uf_w2 = (const float*)d_in[19];
  const float* uf_b2 = (const float*)d_in[20];
  const float* ln1_g = (const float*)d_in[21];
  const float* ln1_b = (const float*)d_in[22];
  const float* ln2_g = (const float*)d_in[23];
  const float* ln2_b = (const float*)d_in[24];
  const float* ln3_g = (const float*)d_in[25];
  const float* ln3_b = (const float*)d_in[26];

  float* ws  = (float*)d_ws;
  float* xnh = ws;                       // 131072 floats
  float* rel = ws + 131072;              // 262144 floats
  float* h   = ws + 393216;              // 8388608 floats (reused as mid)
  float* hu  = ws + 393216 + 8388608;    // 8388608 floats
  float* mid = h;                        // h is dead after K3
  float* out = (float*)d_out;

  k1_knn<<<dim3(BT_/4), dim3(256), 0, stream>>>(ct, cs, x, xnh, rel);
  k2_pe<<<dim3(BT_*NH_/16), dim3(256), 0, stream>>>(rel, xnh, pe_w1, pe_b1, pe_w2, pe_b2,
                                                    ln1_g, ln1_b, h);
  k3_attn<<<dim3(BT_/4), dim3(256), 0, stream>>>(h, xnh, q_w, k_w, v_w, lsc, out_w, out_b,
                                                 nh_w1, nh_b1, nh_w2, nh_b2,
                                                 ln2_g, ln2_b, ln3_g, ln3_b, hu);
  k4_gemm<<<dim3(64, 8), dim3(256), 0, stream>>>(hu, uf_w1, uf_b1, mid);
  k4_gemm<<<dim3(64, 8), dim3(256), 0, stream>>>(mid, uf_w2, uf_b2, out);
}

// Round 3
// 563.468 us; speedup vs baseline: 1.5377x; 1.5377x over previous
//
#include <hip/hip_runtime.h>
#include <math.h>

#define B_ 2
#define T_ 4096
#define S_ 4096
#define NH_ 16
#define MD_ 64
#define FF_ 128
#define H_ 4
#define HD_ 16
#define BT_ (B_*T_)

typedef unsigned short u16;
typedef unsigned int u32;
typedef __attribute__((ext_vector_type(8))) short short8;   // 8 bf16 (4 VGPRs)
typedef __attribute__((ext_vector_type(4))) float f32x4;

__device__ __forceinline__ float wsum64(float v) {
  #pragma unroll
  for (int off = 32; off > 0; off >>= 1) v += __shfl_xor(v, off, 64);
  return v;
}
__device__ __forceinline__ float leaky_(float x) { return x >= 0.f ? x : 0.2f * x; }
__device__ __forceinline__ u16 f2bf(float f) {            // RNE fp32 -> bf16
  u32 u = __float_as_uint(f);
  return (u16)((u + 0x7fffu + ((u >> 16) & 1u)) >> 16);
}
__device__ __forceinline__ float bf2f(u16 h) { return __uint_as_float((u32)h << 16); }

__device__ __forceinline__ void gload16(const void* g, void* l) {
  __builtin_amdgcn_global_load_lds(
      (const __attribute__((address_space(1))) u32*)g,
      (__attribute__((address_space(3))) u32*)l, 16, 0, 0);
}

// ---------------------------------------------------------------------------
// K1: brute-force kNN. One wave per target point. coords_source tile in LDS.
// ---------------------------------------------------------------------------
__global__ __launch_bounds__(256) void k1_knn(
    const float* __restrict__ coords_target, const float* __restrict__ coords_source,
    const float* __restrict__ x, float* __restrict__ xnh, float* __restrict__ rel) {
  __shared__ float2 cs_s[S_];
  const int tid = threadIdx.x;
  const int lane = tid & 63;
  const int n = blockIdx.x * 4 + (tid >> 6);
  const int b = n >> 12;
  const float2* cs = (const float2*)coords_source + (size_t)b * S_;
  for (int i = tid; i < S_; i += 256) cs_s[i] = cs[i];
  __syncthreads();

  const float ctx = coords_target[n*2+0], cty = coords_target[n*2+1];
  float kd[16]; int ki[16];
  #pragma unroll
  for (int j = 0; j < 16; ++j) { kd[j] = INFINITY; ki[j] = 0x7fffffff; }

  for (int kk = 0; kk < 64; ++kk) {
    int s = (kk << 6) | lane;
    float2 c = cs_s[s];
    float dx = ctx - c.x, dy = cty - c.y;
    float d2 = dx*dx + dy*dy;
    if (d2 < kd[15]) {
      float cd = d2; int ci = s;
      #pragma unroll
      for (int j = 0; j < 16; ++j) {
        bool sw = cd < kd[j];
        float td = sw ? kd[j] : cd;  int ti = sw ? ki[j] : ci;
        kd[j]    = sw ? cd : kd[j];  ki[j]    = sw ? ci : ki[j];
        cd = td; ci = ti;
      }
    }
  }

  int myidx = 0;
  for (int r = 0; r < 16; ++r) {
    float hd = kd[0]; int hi = ki[0];
    #pragma unroll
    for (int off = 32; off > 0; off >>= 1) {
      float od = __shfl_xor(hd, off, 64); int oi = __shfl_xor(hi, off, 64);
      bool take = (od < hd) || (od == hd && oi < hi);
      hd = take ? od : hd; hi = take ? oi : hi;
    }
    if (kd[0] == hd && ki[0] == hi) {
      #pragma unroll
      for (int j = 0; j < 15; ++j) { kd[j] = kd[j+1]; ki[j] = ki[j+1]; }
      kd[15] = INFINITY; ki[15] = 0x7fffffff;
    }
    if (lane == r) myidx = hi;
  }

  if (lane < 16) {
    float2 c = cs_s[myidx];
    xnh[(size_t)n*NH_ + lane] = x[(size_t)b*S_ + myidx];
    rel[((size_t)n*NH_ + lane)*2 + 0] = c.x - ctx;
    rel[((size_t)n*NH_ + lane)*2 + 1] = c.y - cty;
  }
}

// ---------------------------------------------------------------------------
// K2: pe MLP (2->128->64) + x_nh add + LN1.
// ---------------------------------------------------------------------------
__global__ __launch_bounds__(256) void k2_pe(
    const float* __restrict__ rel, const float* __restrict__ xnh,
    const float* __restrict__ pe_w1, const float* __restrict__ pe_b1,
    const float* __restrict__ pe_w2, const float* __restrict__ pe_b2,
    const float* __restrict__ ln1_g, const float* __restrict__ ln1_b,
    float* __restrict__ h_out) {
  const int lane = threadIdx.x & 63;
  const int wave = threadIdx.x >> 6;
  __shared__ float hid[4][4][128];
  const int row0 = blockIdx.x * 16 + wave * 4;

  float c0[4], c1[4], xn[4];
  #pragma unroll
  for (int rr = 0; rr < 4; ++rr) {
    int row = row0 + rr;
    float r0 = rel[(size_t)row*2+0], r1 = rel[(size_t)row*2+1];
    float a0 = log1pf(fabsf(r0)), a1 = log1pf(fabsf(r1));
    c0[rr] = r0 > 0.f ? a0 : (r0 < 0.f ? -a0 : 0.f);
    c1[rr] = r1 > 0.f ? a1 : (r1 < 0.f ? -a1 : 0.f);
    xn[rr] = xnh[row];
  }
  const float w1a0 = pe_w1[lane],    w1a1 = pe_w1[128+lane], b1a = pe_b1[lane];
  const float w1b0 = pe_w1[64+lane], w1b1 = pe_w1[192+lane], b1b = pe_b1[64+lane];
  #pragma unroll
  for (int rr = 0; rr < 4; ++rr) {
    hid[wave][rr][lane]    = fmaxf(fmaf(c0[rr], w1a0, fmaf(c1[rr], w1a1, b1a)), 0.f);
    hid[wave][rr][lane+64] = fmaxf(fmaf(c0[rr], w1b0, fmaf(c1[rr], w1b1, b1b)), 0.f);
  }
  __syncthreads();

  const float b2 = pe_b2[lane];
  float acc[4] = {b2, b2, b2, b2};
  for (int j = 0; j < 128; ++j) {
    float w2 = pe_w2[(size_t)j*64 + lane];
    #pragma unroll
    for (int rr = 0; rr < 4; ++rr) acc[rr] = fmaf(hid[wave][rr][j], w2, acc[rr]);
  }

  const float g = ln1_g[lane], bb = ln1_b[lane];
  #pragma unroll
  for (int rr = 0; rr < 4; ++rr) {
    float v = xn[rr] + acc[rr];
    float mu = wsum64(v) * (1.f/64.f);
    float d = v - mu;
    float var = wsum64(d*d) * (1.f/64.f);
    h_out[(size_t)(row0+rr)*64 + lane] = d * rsqrtf(var + 1e-5f) * g + bb;
  }
}

// ---------------------------------------------------------------------------
// K3: fused attention block. Writes hu as bf16 hi/lo split.
// ---------------------------------------------------------------------------
#define QKS 66
#define HTS 20
__global__ __launch_bounds__(256) void k3_attn(
    const float* __restrict__ h_in, const float* __restrict__ xnh,
    const float* __restrict__ q_w, const float* __restrict__ k_w,
    const float* __restrict__ v_w, const float* __restrict__ logit_scale,
    const float* __restrict__ out_w, const float* __restrict__ out_b,
    const float* __restrict__ nh_w1, const float* __restrict__ nh_b1,
    const float* __restrict__ nh_w2, const float* __restrict__ nh_b2,
    const float* __restrict__ ln2_g, const float* __restrict__ ln2_b,
    const float* __restrict__ ln3_g, const float* __restrict__ ln3_b,
    u16* __restrict__ hu_hi, u16* __restrict__ hu_lo) {
  const int lane = threadIdx.x & 63;
  const int wave = threadIdx.x >> 6;
  const int n = blockIdx.x * 4 + wave;
  __shared__ float h_t[4][64][HTS];
  __shared__ float q_s[4][16][QKS];
  __shared__ float k_s[4][16][QKS];
  __shared__ float svx_s[4][16][4];

  const float* hb = h_in + (size_t)n * (NH_*MD_);
  float hr[16];
  #pragma unroll
  for (int i = 0; i < 16; ++i) {
    hr[i] = hb[i*64 + lane];
    h_t[wave][lane][i] = hr[i];
  }
  float xv[16];
  #pragma unroll
  for (int i = 0; i < 16; ++i) xv[i] = xnh[(size_t)n*NH_ + i];

  float wvo[4];
  #pragma unroll
  for (int h = 0; h < 4; ++h) {
    float a = 0.f;
    for (int d = 0; d < 16; ++d)
      a = fmaf(v_w[h*16+d], out_w[(size_t)(h*16+d)*64 + lane], a);
    wvo[h] = a;
  }
  __syncthreads();

  float aq[16], ak[16];
  #pragma unroll
  for (int i = 0; i < 16; ++i) { aq[i] = 0.f; ak[i] = 0.f; }
  for (int c = 0; c < 64; ++c) {
    float qc = q_w[(size_t)c*64 + lane];
    float kc = k_w[(size_t)c*64 + lane];
    #pragma unroll
    for (int i4 = 0; i4 < 4; ++i4) {
      float4 hv = *(const float4*)&h_t[wave][c][i4*4];
      aq[i4*4+0] = fmaf(hv.x, qc, aq[i4*4+0]);
      aq[i4*4+1] = fmaf(hv.y, qc, aq[i4*4+1]);
      aq[i4*4+2] = fmaf(hv.z, qc, aq[i4*4+2]);
      aq[i4*4+3] = fmaf(hv.w, qc, aq[i4*4+3]);
      ak[i4*4+0] = fmaf(hv.x, kc, ak[i4*4+0]);
      ak[i4*4+1] = fmaf(hv.y, kc, ak[i4*4+1]);
      ak[i4*4+2] = fmaf(hv.z, kc, ak[i4*4+2]);
      ak[i4*4+3] = fmaf(hv.w, kc, ak[i4*4+3]);
    }
  }
  #pragma unroll
  for (int i = 0; i < 16; ++i) { q_s[wave][i][lane] = aq[i]; k_s[wave][i][lane] = ak[i]; }
  __syncthreads();

  const int h_id = lane >> 4, i_id = lane & 15;
  float qv[16]; float qs = 0.f;
  #pragma unroll
  for (int d = 0; d < 16; ++d) {
    qv[d] = q_s[wave][i_id][h_id*16+d];
    qs = fmaf(qv[d], qv[d], qs);
  }
  const float rq = 1.f / (sqrtf(qs) + 1e-12f);
  const float sc = expf(fminf(logit_scale[h_id], 4.60517019f));
  float lg[16];
  #pragma unroll
  for (int j = 0; j < 16; ++j) {
    float ks = 0.f, dt = 0.f;
    #pragma unroll
    for (int d = 0; d < 16; ++d) {
      float kv = k_s[wave][j][h_id*16+d];
      ks = fmaf(kv, kv, ks);
      dt = fmaf(qv[d], kv, dt);
    }
    lg[j] = dt * rq * (1.f/(sqrtf(ks)+1e-12f)) * sc;
  }
  float mx = lg[0];
  #pragma unroll
  for (int j = 1; j < 16; ++j) mx = fmaxf(mx, lg[j]);
  float se = 0.f, sx = 0.f;
  #pragma unroll
  for (int j = 0; j < 16; ++j) {
    float e = __expf(lg[j] - mx);
    se += e;
    sx = fmaf(e, xv[j], sx);
  }
  svx_s[wave][i_id][h_id] = sx / se;
  __syncthreads();

  const float ob = out_b[lane], g2 = ln2_g[lane], bb2 = ln2_b[lane];
  float h2[16];
  #pragma unroll
  for (int i = 0; i < 16; ++i) {
    float o = ob;
    #pragma unroll
    for (int h = 0; h < 4; ++h) o = fmaf(svx_s[wave][i][h], wvo[h], o);
    float t = hr[i] + o;
    float mu = wsum64(t) * (1.f/64.f);
    float d = t - mu;
    float var = wsum64(d*d) * (1.f/64.f);
    h2[i] = d * rsqrtf(var + 1e-5f) * g2 + bb2;
  }
  #pragma unroll
  for (int i = 0; i < 16; ++i) h_t[wave][lane][i] = h2[i];
  __syncthreads();

  float ha[16], hc[16];
  const float nb1a = nh_b1[lane], nb1b = nh_b1[64+lane];
  #pragma unroll
  for (int i = 0; i < 16; ++i) { ha[i] = nb1a; hc[i] = nb1b; }
  for (int c = 0; c < 64; ++c) {
    float wa = nh_w1[(size_t)c*128 + lane];
    float wb = nh_w1[(size_t)c*128 + 64 + lane];
    #pragma unroll
    for (int i4 = 0; i4 < 4; ++i4) {
      float4 hv = *(const float4*)&h_t[wave][c][i4*4];
      ha[i4*4+0] = fmaf(hv.x, wa, ha[i4*4+0]); hc[i4*4+0] = fmaf(hv.x, wb, hc[i4*4+0]);
      ha[i4*4+1] = fmaf(hv.y, wa, ha[i4*4+1]); hc[i4*4+1] = fmaf(hv.y, wb, hc[i4*4+1]);
      ha[i4*4+2] = fmaf(hv.z, wa, ha[i4*4+2]); hc[i4*4+2] = fmaf(hv.z, wb, hc[i4*4+2]);
      ha[i4*4+3] = fmaf(hv.w, wa, ha[i4*4+3]); hc[i4*4+3] = fmaf(hv.w, wb, hc[i4*4+3]);
    }
  }
  const float w2a = nh_w2[lane], w2b = nh_w2[64+lane], nb2 = nh_b2[0];
  float h3[16]; float s1 = 0.f, s2 = 0.f;
  #pragma unroll
  for (int i = 0; i < 16; ++i) {
    float pa = fmaf(leaky_(ha[i]), w2a, leaky_(hc[i]) * w2b);
    float sm = wsum64(pa);
    float mi = leaky_(sm + nb2);
    float v3 = h2[i] + mi;
    h3[i] = v3; s1 += v3; s2 = fmaf(v3, v3, s2);
  }

  s1 = wsum64(s1); s2 = wsum64(s2);
  float mu = s1 * (1.f/1024.f);
  float var = s2 * (1.f/1024.f) - mu*mu;
  float rs = rsqrtf(var + 1e-5f);
  const size_t base = (size_t)n * 1024;
  #pragma unroll
  for (int i = 0; i < 16; ++i) {
    int cch = i*64 + lane;
    float v = (h3[i] - mu) * rs * ln3_g[cch] + ln3_b[cch];
    u16 hi = f2bf(v);
    hu_hi[base + cch] = hi;
    hu_lo[base + cch] = f2bf(v - bf2f(hi));
  }
}

// ---------------------------------------------------------------------------
// K0: weight split+transpose: W[K][N] fp32 -> Wt_hi/Wt_lo [N][K] bf16.
// ---------------------------------------------------------------------------
__global__ __launch_bounds__(256) void k0_wsplit(
    const float* __restrict__ W1, const float* __restrict__ W2,
    u16* __restrict__ T1h, u16* __restrict__ T1l,
    u16* __restrict__ T2h, u16* __restrict__ T2l) {
  __shared__ float t[64][65];
  const float* W = blockIdx.z ? W2 : W1;
  u16* Th = blockIdx.z ? T2h : T1h;
  u16* Tl = blockIdx.z ? T2l : T1l;
  const int bx = blockIdx.x * 64, by = blockIdx.y * 64;  // bx: K, by: N
  for (int i = threadIdx.x; i < 64*64; i += 256) {
    int r = i >> 6, c = i & 63;
    t[r][c] = W[(size_t)(bx + r) * 1024 + by + c];
  }
  __syncthreads();
  for (int i = threadIdx.x; i < 64*64; i += 256) {
    int r2 = i >> 6, c2 = i & 63;
    float v = t[c2][r2];
    u16 hi = f2bf(v);
    size_t o = (size_t)(by + r2) * 1024 + bx + c2;
    Th[o] = hi;
    Tl[o] = f2bf(v - bf2f(hi));
  }
}

// ---------------------------------------------------------------------------
// K5: split-bf16 MFMA GEMM. C = leaky(A@W + bias), A: [8192][1024] (hi/lo bf16),
// W given transposed [N][K] (hi/lo bf16). 3-term: AhBh + AhBl + AlBh.
// 128x128 tile, BK=32, 4 waves (2x2), 16x16x32 MFMA, m97 structure.
// ---------------------------------------------------------------------------
template<int OUT_BF16>
__global__ __launch_bounds__(256, 2) void k5_gemm(
    const u16* __restrict__ Ah, const u16* __restrict__ Al,
    const u16* __restrict__ Bth, const u16* __restrict__ Btl,
    const float* __restrict__ bias,
    u16* __restrict__ Chi, u16* __restrict__ Clo, float* __restrict__ Cf) {
  __shared__ u16 As[2][128*32];
  __shared__ u16 Bs[2][128*32];
  const int tid = threadIdx.x;
  const int lane = tid & 63;
  const int wave = tid >> 6;
  const int wr = (wave >> 1) * 64, wc = (wave & 1) * 64;
  const int mt = (int)blockIdx.x >> 3, nt = (int)blockIdx.x & 7;
  const int m0 = mt * 128, n0 = nt * 128;

  const int sr = tid >> 2, sk = (tid & 3) * 8;
  const size_t a_off = (size_t)(m0 + sr) * 1024 + sk;
  const size_t b_off = (size_t)(n0 + sr) * 1024 + sk;
  u16* lAh = &As[0][0] + tid * 8;
  u16* lAl = &As[1][0] + tid * 8;
  u16* lBh = &Bs[0][0] + tid * 8;
  u16* lBl = &Bs[1][0] + tid * 8;

  f32x4 acc[4][4];
  #pragma unroll
  for (int i = 0; i < 4; ++i)
    #pragma unroll
    for (int j = 0; j < 4; ++j) acc[i][j] = (f32x4){0.f, 0.f, 0.f, 0.f};

  const int fr = lane & 15, fq = lane >> 4;
  const int aoff = (wr + fr) * 32 + fq * 8;
  const int boff = (wc + fr) * 32 + fq * 8;

  for (int k0 = 0; k0 < 1024; k0 += 32) {
    __syncthreads();
    gload16(Ah  + a_off + k0,             lAh);
    gload16(Ah  + a_off + k0 + 64*1024,   lAh + 64*32);
    gload16(Al  + a_off + k0,             lAl);
    gload16(Al  + a_off + k0 + 64*1024,   lAl + 64*32);
    gload16(Bth + b_off + k0,             lBh);
    gload16(Bth + b_off + k0 + 64*1024,   lBh + 64*32);
    gload16(Btl + b_off + k0,             lBl);
    gload16(Btl + b_off + k0 + 64*1024,   lBl + 64*32);
    __syncthreads();

    short8 ah[4], al[4], bh[4], bl[4];
    #pragma unroll
    for (int i = 0; i < 4; ++i) {
      ah[i] = *(const short8*)&As[0][aoff + i*16*32];
      al[i] = *(const short8*)&As[1][aoff + i*16*32];
      bh[i] = *(const short8*)&Bs[0][boff + i*16*32];
      bl[i] = *(const short8*)&Bs[1][boff + i*16*32];
    }
    #pragma unroll
    for (int mi = 0; mi < 4; ++mi)
      #pragma unroll
      for (int ni = 0; ni < 4; ++ni) {
        acc[mi][ni] = __builtin_amdgcn_mfma_f32_16x16x32_bf16(ah[mi], bh[ni], acc[mi][ni], 0, 0, 0);
        acc[mi][ni] = __builtin_amdgcn_mfma_f32_16x16x32_bf16(ah[mi], bl[ni], acc[mi][ni], 0, 0, 0);
        acc[mi][ni] = __builtin_amdgcn_mfma_f32_16x16x32_bf16(al[mi], bh[ni], acc[mi][ni], 0, 0, 0);
      }
  }

  #pragma unroll
  for (int mi = 0; mi < 4; ++mi)
    #pragma unroll
    for (int ni = 0; ni < 4; ++ni) {
      const int col = n0 + wc + ni*16 + fr;
      const float bv = bias[col];
      #pragma unroll
      for (int r = 0; r < 4; ++r) {
        const int row = m0 + wr + mi*16 + fq*4 + r;
        float v = leaky_(acc[mi][ni][r] + bv);
        if (OUT_BF16) {
          u16 hi = f2bf(v);
          Chi[(size_t)row*1024 + col] = hi;
          Clo[(size_t)row*1024 + col] = f2bf(v - bf2f(hi));
        } else {
          Cf[(size_t)row*1024 + col] = v;
        }
      }
    }
}

// ---------------------------------------------------------------------------
extern "C" void kernel_launch(void* const* d_in, const int* in_sizes, int n_in,
                              void* d_out, int out_size, void* d_ws, size_t ws_size,
                              hipStream_t stream) {
  (void)in_sizes; (void)n_in; (void)out_size; (void)ws_size;
  const float* x     = (const float*)d_in[0];
  const float* ct    = (const float*)d_in[1];
  const float* cs    = (const float*)d_in[2];
  const float* pe_w1 = (const float*)d_in[3];
  const float* pe_b1 = (const float*)d_in[4];
  const float* pe_w2 = (const float*)d_in[5];
  const float* pe_b2 = (const float*)d_in[6];
  const float* q_w   = (const float*)d_in[7];
  const float* k_w   = (const float*)d_in[8];
  const float* v_w   = (const float*)d_in[9];
  const float* lsc   = (const float*)d_in[10];
  const float* out_w = (const float*)d_in[11];
  const float* out_b = (const float*)d_in[12];
  const float* nh_w1 = (const float*)d_in[13];
  const float* nh_b1 = (const float*)d_in[14];
  const float* nh_w2 = (const float*)d_in[15];
  const float* nh_b2 = (const float*)d_in[16];
  const float* uf_w1 = (const float*)d_in[17];
  const float* uf_b1 = (const float*)d_in[18];
  const float* uf_w2 = (const float*)d_in[19];
  const float* uf_b2 = (const float*)d_in[20];
  const float* ln1_g = (const float*)d_in[21];
  const float* ln1_b = (const float*)d_in[22];
  const float* ln2_g = (const float*)d_in[23];
  const float* ln2_b = (const float*)d_in[24];
  const float* ln3_g = (const float*)d_in[25];
  const float* ln3_b = (const float*)d_in[26];

  float* ws  = (float*)d_ws;
  float* xnh = ws;                                  // 131072 f
  float* rel = ws + 131072;                         // 262144 f
  float* h   = ws + 393216;                         // 8388608 f; dead after k3 -> mid hi/lo
  u16*  hu_hi = (u16*)(ws + 393216 + 8388608);      // 8388608 u16
  u16*  hu_lo = hu_hi + 8388608;                    // 8388608 u16
  u16*  wbase = (u16*)(ws + 393216 + 2*8388608);
  u16*  w1t_hi = wbase;                             // 1048576 u16 each
  u16*  w1t_lo = wbase + 1048576;
  u16*  w2t_hi = wbase + 2*1048576;
  u16*  w2t_lo = wbase + 3*1048576;
  u16*  mid_hi = (u16*)h;                           // alias: h dead after k3
  u16*  mid_lo = mid_hi + 8388608;
  float* out = (float*)d_out;

  k0_wsplit<<<dim3(16, 16, 2), dim3(256), 0, stream>>>(uf_w1, uf_w2,
                                                       w1t_hi, w1t_lo, w2t_hi, w2t_lo);
  k1_knn<<<dim3(BT_/4), dim3(256), 0, stream>>>(ct, cs, x, xnh, rel);
  k2_pe<<<dim3(BT_*NH_/16), dim3(256), 0, stream>>>(rel, xnh, pe_w1, pe_b1, pe_w2, pe_b2,
                                                    ln1_g, ln1_b, h);
  k3_attn<<<dim3(BT_/4), dim3(256), 0, stream>>>(h, xnh, q_w, k_w, v_w, lsc, out_w, out_b,
                                                 nh_w1, nh_b1, nh_w2, nh_b2,
                                                 ln2_g, ln2_b, ln3_g, ln3_b, hu_hi, hu_lo);
  k5_gemm<1><<<dim3(512), dim3(256), 0, stream>>>(hu_hi, hu_lo, w1t_hi, w1t_lo, uf_b1,
                                                  mid_hi, mid_lo, nullptr);
  k5_gemm<0><<<dim3(512), dim3(256), 0, stream>>>(mid_hi, mid_lo, w2t_hi, w2t_lo, uf_b2,
                                                  nullptr, nullptr, out);
}

// Round 4
// 482.362 us; speedup vs baseline: 1.7963x; 1.1681x over previous
//
#include <hip/hip_runtime.h>
#include <math.h>

#define B_ 2
#define T_ 4096
#define S_ 4096
#define NH_ 16
#define MD_ 64
#define FF_ 128
#define H_ 4
#define HD_ 16
#define BT_ (B_*T_)

typedef unsigned short u16;
typedef unsigned int u32;
typedef unsigned long long u64;
typedef __attribute__((ext_vector_type(8))) short short8;   // 8 bf16 (4 VGPRs)
typedef __attribute__((ext_vector_type(4))) float f32x4;

__device__ __forceinline__ float wsum64(float v) {
  #pragma unroll
  for (int off = 32; off > 0; off >>= 1) v += __shfl_xor(v, off, 64);
  return v;
}
__device__ __forceinline__ float leaky_(float x) { return x >= 0.f ? x : 0.2f * x; }
__device__ __forceinline__ u16 f2bf(float f) {            // RNE fp32 -> bf16
  u32 u = __float_as_uint(f);
  return (u16)((u + 0x7fffu + ((u >> 16) & 1u)) >> 16);
}
__device__ __forceinline__ float bf2f(u16 h) { return __uint_as_float((u32)h << 16); }

__device__ __forceinline__ void gload16(const void* g, void* l) {
  __builtin_amdgcn_global_load_lds(
      (const __attribute__((address_space(1))) u32*)g,
      (__attribute__((address_space(3))) u32*)l, 16, 0, 0);
}

__device__ __forceinline__ float dist2_(float2 c, float ctx, float cty) {
  float dx = ctx - c.x, dy = cty - c.y;
  return dx * dx + dy * dy;
}

// ---------------------------------------------------------------------------
// K1: kNN via two-pass threshold filter. One wave per target.
// Pass A: per-lane min over 64 strided candidates -> bitonic sort of 64 lane
//         minima -> tau = 16th smallest (valid upper bound on global 16th d2).
// Pass B: ballot-compact all candidates with d2 <= tau into LDS (E[cnt]~19).
// Exact top-16 by packed (d2_bits,idx) u64 extraction (== top_k tie order).
// Fallback to insert-chain if cnt outside [16,128] (degenerate inputs).
// ---------------------------------------------------------------------------
__global__ __launch_bounds__(256) void k1_knn(
    const float* __restrict__ coords_target, const float* __restrict__ coords_source,
    const float* __restrict__ x, float* __restrict__ xnh, float* __restrict__ rel) {
  __shared__ float2 cs_s[S_];
  __shared__ u64 buf[4][128];
  const int tid = threadIdx.x;
  const int lane = tid & 63;
  const int wave = tid >> 6;
  const int n = blockIdx.x * 4 + wave;
  const int b = n >> 12;                       // T_ = 4096
  const float2* cs = (const float2*)coords_source + (size_t)b * S_;
  for (int i = tid; i < S_; i += 256) cs_s[i] = cs[i];
  __syncthreads();

  const float ctx = coords_target[n*2+0], cty = coords_target[n*2+1];

  // ---- Pass A: per-lane min d2 ----
  float lmin = INFINITY;
  for (int kk = 0; kk < 64; ++kk)
    lmin = fminf(lmin, dist2_(cs_s[(kk << 6) | lane], ctx, cty));

  // bitonic ascending sort of lmin across 64 lanes
  float v = lmin;
  #pragma unroll
  for (int k = 2; k <= 64; k <<= 1) {
    #pragma unroll
    for (int j = k >> 1; j > 0; j >>= 1) {
      float o = __shfl_xor(v, j, 64);
      bool keepmin = (((lane & j) == 0) == ((lane & k) == 0));
      v = keepmin ? fminf(v, o) : fmaxf(v, o);
    }
  }
  const float tau = __shfl(v, 15, 64);   // >= global 16th smallest d2

  // ---- Pass B: collect qualifying candidates ----
  u64* wbuf = buf[wave];
  int cnt = 0;
  for (int kk = 0; kk < 64; ++kk) {
    int s = (kk << 6) | lane;
    float d2 = dist2_(cs_s[s], ctx, cty);
    bool q = (d2 <= tau);
    u64 mask = __ballot(q);
    if (q) {
      int pos = cnt + __popcll(mask & ((1ull << lane) - 1ull));
      if (pos < 128)
        wbuf[pos] = ((u64)__float_as_uint(d2) << 32) | (u32)s;
    }
    cnt += (int)__popcll(mask);
  }

  int myidx = 0;
  if (cnt >= 16 && cnt <= 128) {
    // ---- exact extraction of 16 smallest (lex by (d2, idx)) ----
    u64 c0 = (lane < cnt) ? wbuf[lane] : ~0ull;
    u64 c1 = (lane + 64 < cnt) ? wbuf[lane + 64] : ~0ull;
    for (int r = 0; r < 16; ++r) {
      u64 m = c0 < c1 ? c0 : c1;
      #pragma unroll
      for (int off = 32; off > 0; off >>= 1) {
        u64 o = __shfl_xor(m, off, 64);
        m = o < m ? o : m;
      }
      if (lane == r) myidx = (int)(u32)(m & 0xffffffffu);
      if (c0 == m) c0 = ~0ull;
      else if (c1 == m) c1 = ~0ull;
    }
  } else {
    // ---- fallback: verified insert-chain path (degenerate inputs only) ----
    float kd[16]; int ki[16];
    #pragma unroll
    for (int j = 0; j < 16; ++j) { kd[j] = INFINITY; ki[j] = 0x7fffffff; }
    for (int kk = 0; kk < 64; ++kk) {
      int s = (kk << 6) | lane;
      float d2 = dist2_(cs_s[s], ctx, cty);
      if (d2 < kd[15]) {
        float cd = d2; int ci = s;
        #pragma unroll
        for (int j = 0; j < 16; ++j) {
          bool sw = cd < kd[j];
          float td = sw ? kd[j] : cd;  int ti = sw ? ki[j] : ci;
          kd[j]    = sw ? cd : kd[j];  ki[j]    = sw ? ci : ki[j];
          cd = td; ci = ti;
        }
      }
    }
    for (int r = 0; r < 16; ++r) {
      float hd = kd[0]; int hi = ki[0];
      #pragma unroll
      for (int off = 32; off > 0; off >>= 1) {
        float od = __shfl_xor(hd, off, 64); int oi = __shfl_xor(hi, off, 64);
        bool take = (od < hd) || (od == hd && oi < hi);
        hd = take ? od : hd; hi = take ? oi : hi;
      }
      if (kd[0] == hd && ki[0] == hi) {
        #pragma unroll
        for (int j = 0; j < 15; ++j) { kd[j] = kd[j+1]; ki[j] = ki[j+1]; }
        kd[15] = INFINITY; ki[15] = 0x7fffffff;
      }
      if (lane == r) myidx = hi;
    }
  }

  if (lane < 16) {
    float2 c = cs_s[myidx];
    xnh[(size_t)n*NH_ + lane] = x[(size_t)b*S_ + myidx];
    rel[((size_t)n*NH_ + lane)*2 + 0] = c.x - ctx;
    rel[((size_t)n*NH_ + lane)*2 + 1] = c.y - cty;
  }
}

// ---------------------------------------------------------------------------
// K2: pe MLP (2->128->64) + x_nh add + LN1. (unchanged)
// ---------------------------------------------------------------------------
__global__ __launch_bounds__(256) void k2_pe(
    const float* __restrict__ rel, const float* __restrict__ xnh,
    const float* __restrict__ pe_w1, const float* __restrict__ pe_b1,
    const float* __restrict__ pe_w2, const float* __restrict__ pe_b2,
    const float* __restrict__ ln1_g, const float* __restrict__ ln1_b,
    float* __restrict__ h_out) {
  const int lane = threadIdx.x & 63;
  const int wave = threadIdx.x >> 6;
  __shared__ float hid[4][4][128];
  const int row0 = blockIdx.x * 16 + wave * 4;

  float c0[4], c1[4], xn[4];
  #pragma unroll
  for (int rr = 0; rr < 4; ++rr) {
    int row = row0 + rr;
    float r0 = rel[(size_t)row*2+0], r1 = rel[(size_t)row*2+1];
    float a0 = log1pf(fabsf(r0)), a1 = log1pf(fabsf(r1));
    c0[rr] = r0 > 0.f ? a0 : (r0 < 0.f ? -a0 : 0.f);
    c1[rr] = r1 > 0.f ? a1 : (r1 < 0.f ? -a1 : 0.f);
    xn[rr] = xnh[row];
  }
  const float w1a0 = pe_w1[lane],    w1a1 = pe_w1[128+lane], b1a = pe_b1[lane];
  const float w1b0 = pe_w1[64+lane], w1b1 = pe_w1[192+lane], b1b = pe_b1[64+lane];
  #pragma unroll
  for (int rr = 0; rr < 4; ++rr) {
    hid[wave][rr][lane]    = fmaxf(fmaf(c0[rr], w1a0, fmaf(c1[rr], w1a1, b1a)), 0.f);
    hid[wave][rr][lane+64] = fmaxf(fmaf(c0[rr], w1b0, fmaf(c1[rr], w1b1, b1b)), 0.f);
  }
  __syncthreads();

  const float b2 = pe_b2[lane];
  float acc[4] = {b2, b2, b2, b2};
  for (int j = 0; j < 128; ++j) {
    float w2 = pe_w2[(size_t)j*64 + lane];
    #pragma unroll
    for (int rr = 0; rr < 4; ++rr) acc[rr] = fmaf(hid[wave][rr][j], w2, acc[rr]);
  }

  const float g = ln1_g[lane], bb = ln1_b[lane];
  #pragma unroll
  for (int rr = 0; rr < 4; ++rr) {
    float v = xn[rr] + acc[rr];
    float mu = wsum64(v) * (1.f/64.f);
    float d = v - mu;
    float var = wsum64(d*d) * (1.f/64.f);
    h_out[(size_t)(row0+rr)*64 + lane] = d * rsqrtf(var + 1e-5f) * g + bb;
  }
}

// ---------------------------------------------------------------------------
// K3: fused attention block. Writes hu as bf16 hi/lo split. (unchanged)
// ---------------------------------------------------------------------------
#define QKS 66
#define HTS 20
__global__ __launch_bounds__(256) void k3_attn(
    const float* __restrict__ h_in, const float* __restrict__ xnh,
    const float* __restrict__ q_w, const float* __restrict__ k_w,
    const float* __restrict__ v_w, const float* __restrict__ logit_scale,
    const float* __restrict__ out_w, const float* __restrict__ out_b,
    const float* __restrict__ nh_w1, const float* __restrict__ nh_b1,
    const float* __restrict__ nh_w2, const float* __restrict__ nh_b2,
    const float* __restrict__ ln2_g, const float* __restrict__ ln2_b,
    const float* __restrict__ ln3_g, const float* __restrict__ ln3_b,
    u16* __restrict__ hu_hi, u16* __restrict__ hu_lo) {
  const int lane = threadIdx.x & 63;
  const int wave = threadIdx.x >> 6;
  const int n = blockIdx.x * 4 + wave;
  __shared__ float h_t[4][64][HTS];
  __shared__ float q_s[4][16][QKS];
  __shared__ float k_s[4][16][QKS];
  __shared__ float svx_s[4][16][4];

  const float* hb = h_in + (size_t)n * (NH_*MD_);
  float hr[16];
  #pragma unroll
  for (int i = 0; i < 16; ++i) {
    hr[i] = hb[i*64 + lane];
    h_t[wave][lane][i] = hr[i];
  }
  float xv[16];
  #pragma unroll
  for (int i = 0; i < 16; ++i) xv[i] = xnh[(size_t)n*NH_ + i];

  float wvo[4];
  #pragma unroll
  for (int h = 0; h < 4; ++h) {
    float a = 0.f;
    for (int d = 0; d < 16; ++d)
      a = fmaf(v_w[h*16+d], out_w[(size_t)(h*16+d)*64 + lane], a);
    wvo[h] = a;
  }
  __syncthreads();

  float aq[16], ak[16];
  #pragma unroll
  for (int i = 0; i < 16; ++i) { aq[i] = 0.f; ak[i] = 0.f; }
  for (int c = 0; c < 64; ++c) {
    float qc = q_w[(size_t)c*64 + lane];
    float kc = k_w[(size_t)c*64 + lane];
    #pragma unroll
    for (int i4 = 0; i4 < 4; ++i4) {
      float4 hv = *(const float4*)&h_t[wave][c][i4*4];
      aq[i4*4+0] = fmaf(hv.x, qc, aq[i4*4+0]);
      aq[i4*4+1] = fmaf(hv.y, qc, aq[i4*4+1]);
      aq[i4*4+2] = fmaf(hv.z, qc, aq[i4*4+2]);
      aq[i4*4+3] = fmaf(hv.w, qc, aq[i4*4+3]);
      ak[i4*4+0] = fmaf(hv.x, kc, ak[i4*4+0]);
      ak[i4*4+1] = fmaf(hv.y, kc, ak[i4*4+1]);
      ak[i4*4+2] = fmaf(hv.z, kc, ak[i4*4+2]);
      ak[i4*4+3] = fmaf(hv.w, kc, ak[i4*4+3]);
    }
  }
  #pragma unroll
  for (int i = 0; i < 16; ++i) { q_s[wave][i][lane] = aq[i]; k_s[wave][i][lane] = ak[i]; }
  __syncthreads();

  const int h_id = lane >> 4, i_id = lane & 15;
  float qv[16]; float qs = 0.f;
  #pragma unroll
  for (int d = 0; d < 16; ++d) {
    qv[d] = q_s[wave][i_id][h_id*16+d];
    qs = fmaf(qv[d], qv[d], qs);
  }
  const float rq = 1.f / (sqrtf(qs) + 1e-12f);
  const float sc = expf(fminf(logit_scale[h_id], 4.60517019f));
  float lg[16];
  #pragma unroll
  for (int j = 0; j < 16; ++j) {
    float ks = 0.f, dt = 0.f;
    #pragma unroll
    for (int d = 0; d < 16; ++d) {
      float kv = k_s[wave][j][h_id*16+d];
      ks = fmaf(kv, kv, ks);
      dt = fmaf(qv[d], kv, dt);
    }
    lg[j] = dt * rq * (1.f/(sqrtf(ks)+1e-12f)) * sc;
  }
  float mx = lg[0];
  #pragma unroll
  for (int j = 1; j < 16; ++j) mx = fmaxf(mx, lg[j]);
  float se = 0.f, sx = 0.f;
  #pragma unroll
  for (int j = 0; j < 16; ++j) {
    float e = __expf(lg[j] - mx);
    se += e;
    sx = fmaf(e, xv[j], sx);
  }
  svx_s[wave][i_id][h_id] = sx / se;
  __syncthreads();

  const float ob = out_b[lane], g2 = ln2_g[lane], bb2 = ln2_b[lane];
  float h2[16];
  #pragma unroll
  for (int i = 0; i < 16; ++i) {
    float o = ob;
    #pragma unroll
    for (int h = 0; h < 4; ++h) o = fmaf(svx_s[wave][i][h], wvo[h], o);
    float t = hr[i] + o;
    float mu = wsum64(t) * (1.f/64.f);
    float d = t - mu;
    float var = wsum64(d*d) * (1.f/64.f);
    h2[i] = d * rsqrtf(var + 1e-5f) * g2 + bb2;
  }
  #pragma unroll
  for (int i = 0; i < 16; ++i) h_t[wave][lane][i] = h2[i];
  __syncthreads();

  float ha[16], hc[16];
  const float nb1a = nh_b1[lane], nb1b = nh_b1[64+lane];
  #pragma unroll
  for (int i = 0; i < 16; ++i) { ha[i] = nb1a; hc[i] = nb1b; }
  for (int c = 0; c < 64; ++c) {
    float wa = nh_w1[(size_t)c*128 + lane];
    float wb = nh_w1[(size_t)c*128 + 64 + lane];
    #pragma unroll
    for (int i4 = 0; i4 < 4; ++i4) {
      float4 hv = *(const float4*)&h_t[wave][c][i4*4];
      ha[i4*4+0] = fmaf(hv.x, wa, ha[i4*4+0]); hc[i4*4+0] = fmaf(hv.x, wb, hc[i4*4+0]);
      ha[i4*4+1] = fmaf(hv.y, wa, ha[i4*4+1]); hc[i4*4+1] = fmaf(hv.y, wb, hc[i4*4+1]);
      ha[i4*4+2] = fmaf(hv.z, wa, ha[i4*4+2]); hc[i4*4+2] = fmaf(hv.z, wb, hc[i4*4+2]);
      ha[i4*4+3] = fmaf(hv.w, wa, ha[i4*4+3]); hc[i4*4+3] = fmaf(hv.w, wb, hc[i4*4+3]);
    }
  }
  const float w2a = nh_w2[lane], w2b = nh_w2[64+lane], nb2 = nh_b2[0];
  float h3[16]; float s1 = 0.f, s2 = 0.f;
  #pragma unroll
  for (int i = 0; i < 16; ++i) {
    float pa = fmaf(leaky_(ha[i]), w2a, leaky_(hc[i]) * w2b);
    float sm = wsum64(pa);
    float mi = leaky_(sm + nb2);
    float v3 = h2[i] + mi;
    h3[i] = v3; s1 += v3; s2 = fmaf(v3, v3, s2);
  }

  s1 = wsum64(s1); s2 = wsum64(s2);
  float mu = s1 * (1.f/1024.f);
  float var = s2 * (1.f/1024.f) - mu*mu;
  float rs = rsqrtf(var + 1e-5f);
  const size_t base = (size_t)n * 1024;
  #pragma unroll
  for (int i = 0; i < 16; ++i) {
    int cch = i*64 + lane;
    float v = (h3[i] - mu) * rs * ln3_g[cch] + ln3_b[cch];
    u16 hi = f2bf(v);
    hu_hi[base + cch] = hi;
    hu_lo[base + cch] = f2bf(v - bf2f(hi));
  }
}

// ---------------------------------------------------------------------------
// K0: weight split+transpose: W[K][N] fp32 -> Wt_hi/Wt_lo [N][K] bf16.
// ---------------------------------------------------------------------------
__global__ __launch_bounds__(256) void k0_wsplit(
    const float* __restrict__ W1, const float* __restrict__ W2,
    u16* __restrict__ T1h, u16* __restrict__ T1l,
    u16* __restrict__ T2h, u16* __restrict__ T2l) {
  __shared__ float t[64][65];
  const float* W = blockIdx.z ? W2 : W1;
  u16* Th = blockIdx.z ? T2h : T1h;
  u16* Tl = blockIdx.z ? T2l : T1l;
  const int bx = blockIdx.x * 64, by = blockIdx.y * 64;  // bx: K, by: N
  for (int i = threadIdx.x; i < 64*64; i += 256) {
    int r = i >> 6, c = i & 63;
    t[r][c] = W[(size_t)(bx + r) * 1024 + by + c];
  }
  __syncthreads();
  for (int i = threadIdx.x; i < 64*64; i += 256) {
    int r2 = i >> 6, c2 = i & 63;
    float v = t[c2][r2];
    u16 hi = f2bf(v);
    size_t o = (size_t)(by + r2) * 1024 + bx + c2;
    Th[o] = hi;
    Tl[o] = f2bf(v - bf2f(hi));
  }
}

// ---------------------------------------------------------------------------
// K5: split-bf16 MFMA GEMM. (unchanged)
// ---------------------------------------------------------------------------
template<int OUT_BF16>
__global__ __launch_bounds__(256, 2) void k5_gemm(
    const u16* __restrict__ Ah, const u16* __restrict__ Al,
    const u16* __restrict__ Bth, const u16* __restrict__ Btl,
    const float* __restrict__ bias,
    u16* __restrict__ Chi, u16* __restrict__ Clo, float* __restrict__ Cf) {
  __shared__ u16 As[2][128*32];
  __shared__ u16 Bs[2][128*32];
  const int tid = threadIdx.x;
  const int lane = tid & 63;
  const int wave = tid >> 6;
  const int wr = (wave >> 1) * 64, wc = (wave & 1) * 64;
  const int mt = (int)blockIdx.x >> 3, nt = (int)blockIdx.x & 7;
  const int m0 = mt * 128, n0 = nt * 128;

  const int sr = tid >> 2, sk = (tid & 3) * 8;
  const size_t a_off = (size_t)(m0 + sr) * 1024 + sk;
  const size_t b_off = (size_t)(n0 + sr) * 1024 + sk;
  u16* lAh = &As[0][0] + tid * 8;
  u16* lAl = &As[1][0] + tid * 8;
  u16* lBh = &Bs[0][0] + tid * 8;
  u16* lBl = &Bs[1][0] + tid * 8;

  f32x4 acc[4][4];
  #pragma unroll
  for (int i = 0; i < 4; ++i)
    #pragma unroll
    for (int j = 0; j < 4; ++j) acc[i][j] = (f32x4){0.f, 0.f, 0.f, 0.f};

  const int fr = lane & 15, fq = lane >> 4;
  const int aoff = (wr + fr) * 32 + fq * 8;
  const int boff = (wc + fr) * 32 + fq * 8;

  for (int k0 = 0; k0 < 1024; k0 += 32) {
    __syncthreads();
    gload16(Ah  + a_off + k0,             lAh);
    gload16(Ah  + a_off + k0 + 64*1024,   lAh + 64*32);
    gload16(Al  + a_off + k0,             lAl);
    gload16(Al  + a_off + k0 + 64*1024,   lAl + 64*32);
    gload16(Bth + b_off + k0,             lBh);
    gload16(Bth + b_off + k0 + 64*1024,   lBh + 64*32);
    gload16(Btl + b_off + k0,             lBl);
    gload16(Btl + b_off + k0 + 64*1024,   lBl + 64*32);
    __syncthreads();

    short8 ah[4], al[4], bh[4], bl[4];
    #pragma unroll
    for (int i = 0; i < 4; ++i) {
      ah[i] = *(const short8*)&As[0][aoff + i*16*32];
      al[i] = *(const short8*)&As[1][aoff + i*16*32];
      bh[i] = *(const short8*)&Bs[0][boff + i*16*32];
      bl[i] = *(const short8*)&Bs[1][boff + i*16*32];
    }
    #pragma unroll
    for (int mi = 0; mi < 4; ++mi)
      #pragma unroll
      for (int ni = 0; ni < 4; ++ni) {
        acc[mi][ni] = __builtin_amdgcn_mfma_f32_16x16x32_bf16(ah[mi], bh[ni], acc[mi][ni], 0, 0, 0);
        acc[mi][ni] = __builtin_amdgcn_mfma_f32_16x16x32_bf16(ah[mi], bl[ni], acc[mi][ni], 0, 0, 0);
        acc[mi][ni] = __builtin_amdgcn_mfma_f32_16x16x32_bf16(al[mi], bh[ni], acc[mi][ni], 0, 0, 0);
      }
  }

  #pragma unroll
  for (int mi = 0; mi < 4; ++mi)
    #pragma unroll
    for (int ni = 0; ni < 4; ++ni) {
      const int col = n0 + wc + ni*16 + fr;
      const float bv = bias[col];
      #pragma unroll
      for (int r = 0; r < 4; ++r) {
        const int row = m0 + wr + mi*16 + fq*4 + r;
        float v = leaky_(acc[mi][ni][r] + bv);
        if (OUT_BF16) {
          u16 hi = f2bf(v);
          Chi[(size_t)row*1024 + col] = hi;
          Clo[(size_t)row*1024 + col] = f2bf(v - bf2f(hi));
        } else {
          Cf[(size_t)row*1024 + col] = v;
        }
      }
    }
}

// ---------------------------------------------------------------------------
extern "C" void kernel_launch(void* const* d_in, const int* in_sizes, int n_in,
                              void* d_out, int out_size, void* d_ws, size_t ws_size,
                              hipStream_t stream) {
  (void)in_sizes; (void)n_in; (void)out_size; (void)ws_size;
  const float* x     = (const float*)d_in[0];
  const float* ct    = (const float*)d_in[1];
  const float* cs    = (const float*)d_in[2];
  const float* pe_w1 = (const float*)d_in[3];
  const float* pe_b1 = (const float*)d_in[4];
  const float* pe_w2 = (const float*)d_in[5];
  const float* pe_b2 = (const float*)d_in[6];
  const float* q_w   = (const float*)d_in[7];
  const float* k_w   = (const float*)d_in[8];
  const float* v_w   = (const float*)d_in[9];
  const float* lsc   = (const float*)d_in[10];
  const float* out_w = (const float*)d_in[11];
  const float* out_b = (const float*)d_in[12];
  const float* nh_w1 = (const float*)d_in[13];
  const float* nh_b1 = (const float*)d_in[14];
  const float* nh_w2 = (const float*)d_in[15];
  const float* nh_b2 = (const float*)d_in[16];
  const float* uf_w1 = (const float*)d_in[17];
  const float* uf_b1 = (const float*)d_in[18];
  const float* uf_w2 = (const float*)d_in[19];
  const float* uf_b2 = (const float*)d_in[20];
  const float* ln1_g = (const float*)d_in[21];
  const float* ln1_b = (const float*)d_in[22];
  const float* ln2_g = (const float*)d_in[23];
  const float* ln2_b = (const float*)d_in[24];
  const float* ln3_g = (const float*)d_in[25];
  const float* ln3_b = (const float*)d_in[26];

  float* ws  = (float*)d_ws;
  float* xnh = ws;                                  // 131072 f
  float* rel = ws + 131072;                         // 262144 f
  float* h   = ws + 393216;                         // 8388608 f; dead after k3 -> mid hi/lo
  u16*  hu_hi = (u16*)(ws + 393216 + 8388608);      // 8388608 u16
  u16*  hu_lo = hu_hi + 8388608;                    // 8388608 u16
  u16*  wbase = (u16*)(ws + 393216 + 2*8388608);
  u16*  w1t_hi = wbase;                             // 1048576 u16 each
  u16*  w1t_lo = wbase + 1048576;
  u16*  w2t_hi = wbase + 2*1048576;
  u16*  w2t_lo = wbase + 3*1048576;
  u16*  mid_hi = (u16*)h;                           // alias: h dead after k3
  u16*  mid_lo = mid_hi + 8388608;
  float* out = (float*)d_out;

  k0_wsplit<<<dim3(16, 16, 2), dim3(256), 0, stream>>>(uf_w1, uf_w2,
                                                       w1t_hi, w1t_lo, w2t_hi, w2t_lo);
  k1_knn<<<dim3(BT_/4), dim3(256), 0, stream>>>(ct, cs, x, xnh, rel);
  k2_pe<<<dim3(BT_*NH_/16), dim3(256), 0, stream>>>(rel, xnh, pe_w1, pe_b1, pe_w2, pe_b2,
                                                    ln1_g, ln1_b, h);
  k3_attn<<<dim3(BT_/4), dim3(256), 0, stream>>>(h, xnh, q_w, k_w, v_w, lsc, out_w, out_b,
                                                 nh_w1, nh_b1, nh_w2, nh_b2,
                                                 ln2_g, ln2_b, ln3_g, ln3_b, hu_hi, hu_lo);
  k5_gemm<1><<<dim3(512), dim3(256), 0, stream>>>(hu_hi, hu_lo, w1t_hi, w1t_lo, uf_b1,
                                                  mid_hi, mid_lo, nullptr);
  k5_gemm<0><<<dim3(512), dim3(256), 0, stream>>>(mid_hi, mid_lo, w2t_hi, w2t_lo, uf_b2,
                                                  nullptr, nullptr, out);
}

// Round 6
// 466.468 us; speedup vs baseline: 1.8575x; 1.0341x over previous
//
#include <hip/hip_runtime.h>
#include <math.h>

#define B_ 2
#define T_ 4096
#define S_ 4096
#define NH_ 16
#define MD_ 64
#define FF_ 128
#define H_ 4
#define HD_ 16
#define BT_ (B_*T_)

typedef unsigned short u16;
typedef unsigned int u32;
typedef unsigned long long u64;
typedef __attribute__((ext_vector_type(8))) short short8;   // 8 bf16 (4 VGPRs)
typedef __attribute__((ext_vector_type(4))) float f32x4;

__device__ __forceinline__ float wsum64(float v) {
  #pragma unroll
  for (int off = 32; off > 0; off >>= 1) v += __shfl_xor(v, off, 64);
  return v;
}
__device__ __forceinline__ float leaky_(float x) { return x >= 0.f ? x : 0.2f * x; }
__device__ __forceinline__ u16 f2bf(float f) {            // RNE fp32 -> bf16
  u32 u = __float_as_uint(f);
  return (u16)((u + 0x7fffu + ((u >> 16) & 1u)) >> 16);
}
__device__ __forceinline__ float bf2f(u16 h) { return __uint_as_float((u32)h << 16); }

__device__ __forceinline__ void gload16(const void* g, void* l) {
  __builtin_amdgcn_global_load_lds(
      (const __attribute__((address_space(1))) u32*)g,
      (__attribute__((address_space(3))) u32*)l, 16, 0, 0);
}

__device__ __forceinline__ float dist2_(float2 c, float ctx, float cty) {
  float dx = ctx - c.x, dy = cty - c.y;
  return dx * dx + dy * dy;
}

// ---------------------------------------------------------------------------
// K1: kNN via two-pass threshold filter. (unchanged, verified)
// ---------------------------------------------------------------------------
__global__ __launch_bounds__(256) void k1_knn(
    const float* __restrict__ coords_target, const float* __restrict__ coords_source,
    const float* __restrict__ x, float* __restrict__ xnh, float* __restrict__ rel) {
  __shared__ float2 cs_s[S_];
  __shared__ u64 buf[4][128];
  const int tid = threadIdx.x;
  const int lane = tid & 63;
  const int wave = tid >> 6;
  const int n = blockIdx.x * 4 + wave;
  const int b = n >> 12;
  const float2* cs = (const float2*)coords_source + (size_t)b * S_;
  for (int i = tid; i < S_; i += 256) cs_s[i] = cs[i];
  __syncthreads();

  const float ctx = coords_target[n*2+0], cty = coords_target[n*2+1];

  float lmin = INFINITY;
  for (int kk = 0; kk < 64; ++kk)
    lmin = fminf(lmin, dist2_(cs_s[(kk << 6) | lane], ctx, cty));

  float v = lmin;
  #pragma unroll
  for (int k = 2; k <= 64; k <<= 1) {
    #pragma unroll
    for (int j = k >> 1; j > 0; j >>= 1) {
      float o = __shfl_xor(v, j, 64);
      bool keepmin = (((lane & j) == 0) == ((lane & k) == 0));
      v = keepmin ? fminf(v, o) : fmaxf(v, o);
    }
  }
  const float tau = __shfl(v, 15, 64);

  u64* wbuf = buf[wave];
  int cnt = 0;
  for (int kk = 0; kk < 64; ++kk) {
    int s = (kk << 6) | lane;
    float d2 = dist2_(cs_s[s], ctx, cty);
    bool q = (d2 <= tau);
    u64 mask = __ballot(q);
    if (q) {
      int pos = cnt + __popcll(mask & ((1ull << lane) - 1ull));
      if (pos < 128)
        wbuf[pos] = ((u64)__float_as_uint(d2) << 32) | (u32)s;
    }
    cnt += (int)__popcll(mask);
  }

  int myidx = 0;
  if (cnt >= 16 && cnt <= 128) {
    u64 c0 = (lane < cnt) ? wbuf[lane] : ~0ull;
    u64 c1 = (lane + 64 < cnt) ? wbuf[lane + 64] : ~0ull;
    for (int r = 0; r < 16; ++r) {
      u64 m = c0 < c1 ? c0 : c1;
      #pragma unroll
      for (int off = 32; off > 0; off >>= 1) {
        u64 o = __shfl_xor(m, off, 64);
        m = o < m ? o : m;
      }
      if (lane == r) myidx = (int)(u32)(m & 0xffffffffu);
      if (c0 == m) c0 = ~0ull;
      else if (c1 == m) c1 = ~0ull;
    }
  } else {
    float kd[16]; int ki[16];
    #pragma unroll
    for (int j = 0; j < 16; ++j) { kd[j] = INFINITY; ki[j] = 0x7fffffff; }
    for (int kk = 0; kk < 64; ++kk) {
      int s = (kk << 6) | lane;
      float d2 = dist2_(cs_s[s], ctx, cty);
      if (d2 < kd[15]) {
        float cd = d2; int ci = s;
        #pragma unroll
        for (int j = 0; j < 16; ++j) {
          bool sw = cd < kd[j];
          float td = sw ? kd[j] : cd;  int ti = sw ? ki[j] : ci;
          kd[j]    = sw ? cd : kd[j];  ki[j]    = sw ? ci : ki[j];
          cd = td; ci = ti;
        }
      }
    }
    for (int r = 0; r < 16; ++r) {
      float hd = kd[0]; int hi = ki[0];
      #pragma unroll
      for (int off = 32; off > 0; off >>= 1) {
        float od = __shfl_xor(hd, off, 64); int oi = __shfl_xor(hi, off, 64);
        bool take = (od < hd) || (od == hd && oi < hi);
        hd = take ? od : hd; hi = take ? oi : hi;
      }
      if (kd[0] == hd && ki[0] == hi) {
        #pragma unroll
        for (int j = 0; j < 15; ++j) { kd[j] = kd[j+1]; ki[j] = ki[j+1]; }
        kd[15] = INFINITY; ki[15] = 0x7fffffff;
      }
      if (lane == r) myidx = hi;
    }
  }

  if (lane < 16) {
    float2 c = cs_s[myidx];
    xnh[(size_t)n*NH_ + lane] = x[(size_t)b*S_ + myidx];
    rel[((size_t)n*NH_ + lane)*2 + 0] = c.x - ctx;
    rel[((size_t)n*NH_ + lane)*2 + 1] = c.y - cty;
  }
}

// ---------------------------------------------------------------------------
// K2: pe MLP (2->128->64) + x_nh add + LN1. (unchanged)
// ---------------------------------------------------------------------------
__global__ __launch_bounds__(256) void k2_pe(
    const float* __restrict__ rel, const float* __restrict__ xnh,
    const float* __restrict__ pe_w1, const float* __restrict__ pe_b1,
    const float* __restrict__ pe_w2, const float* __restrict__ pe_b2,
    const float* __restrict__ ln1_g, const float* __restrict__ ln1_b,
    float* __restrict__ h_out) {
  const int lane = threadIdx.x & 63;
  const int wave = threadIdx.x >> 6;
  __shared__ float hid[4][4][128];
  const int row0 = blockIdx.x * 16 + wave * 4;

  float c0[4], c1[4], xn[4];
  #pragma unroll
  for (int rr = 0; rr < 4; ++rr) {
    int row = row0 + rr;
    float r0 = rel[(size_t)row*2+0], r1 = rel[(size_t)row*2+1];
    float a0 = log1pf(fabsf(r0)), a1 = log1pf(fabsf(r1));
    c0[rr] = r0 > 0.f ? a0 : (r0 < 0.f ? -a0 : 0.f);
    c1[rr] = r1 > 0.f ? a1 : (r1 < 0.f ? -a1 : 0.f);
    xn[rr] = xnh[row];
  }
  const float w1a0 = pe_w1[lane],    w1a1 = pe_w1[128+lane], b1a = pe_b1[lane];
  const float w1b0 = pe_w1[64+lane], w1b1 = pe_w1[192+lane], b1b = pe_b1[64+lane];
  #pragma unroll
  for (int rr = 0; rr < 4; ++rr) {
    hid[wave][rr][lane]    = fmaxf(fmaf(c0[rr], w1a0, fmaf(c1[rr], w1a1, b1a)), 0.f);
    hid[wave][rr][lane+64] = fmaxf(fmaf(c0[rr], w1b0, fmaf(c1[rr], w1b1, b1b)), 0.f);
  }
  __syncthreads();

  const float b2 = pe_b2[lane];
  float acc[4] = {b2, b2, b2, b2};
  for (int j = 0; j < 128; ++j) {
    float w2 = pe_w2[(size_t)j*64 + lane];
    #pragma unroll
    for (int rr = 0; rr < 4; ++rr) acc[rr] = fmaf(hid[wave][rr][j], w2, acc[rr]);
  }

  const float g = ln1_g[lane], bb = ln1_b[lane];
  #pragma unroll
  for (int rr = 0; rr < 4; ++rr) {
    float v = xn[rr] + acc[rr];
    float mu = wsum64(v) * (1.f/64.f);
    float d = v - mu;
    float var = wsum64(d*d) * (1.f/64.f);
    h_out[(size_t)(row0+rr)*64 + lane] = d * rsqrtf(var + 1e-5f) * g + bb;
  }
}

// ---------------------------------------------------------------------------
// K3: fused attention block, MFMA-ized.
// Per block: 4 targets (n), 64 rows. Phases:
//  1. load h rows -> regs + LDS bf16 hi/lo (padded stride 72)
//  2. q/k projection via MFMA (wave w = head w: q cols w*16.., k cols 64+w*16..)
//     B-frags straight from global (pre-split/transposed qkwt). D -> q_s/k_s bf16.
//  3. attention: lane = block row, head = wave. In-lane softmax. svx -> LDS.
//  4. factorized out-proj + residual + LN2 (lane = channel) -> h2; h2 -> LDS planes.
//  5. nh MLP layer-1 via MFMA (wave w = cols w*32..+31) + fused leaky+dot(nh_w2)
//     + 16-lane xor reduce -> mred.
//  6. m broadcast + residual + LN3 -> hu hi/lo.
// ---------------------------------------------------------------------------
#define HBF_S 72   // h_bf row stride in u16 (144 B: 16B-aligned, no pow2 conflicts)
#define QKS2 24    // q_s/k_s row stride in u16 (48 B: 16B-aligned)
__global__ __launch_bounds__(256) void k3_attn(
    const float* __restrict__ h_in, const float* __restrict__ xnh,
    const u16* __restrict__ qkwt_hi, const u16* __restrict__ qkwt_lo,
    const u16* __restrict__ nhw1t_hi, const u16* __restrict__ nhw1t_lo,
    const float* __restrict__ v_w, const float* __restrict__ logit_scale,
    const float* __restrict__ out_w, const float* __restrict__ out_b,
    const float* __restrict__ nh_b1, const float* __restrict__ nh_w2,
    const float* __restrict__ nh_b2,
    const float* __restrict__ ln2_g, const float* __restrict__ ln2_b,
    const float* __restrict__ ln3_g, const float* __restrict__ ln3_b,
    u16* __restrict__ hu_hi, u16* __restrict__ hu_lo) {
  const int tid = threadIdx.x;
  const int lane = tid & 63;
  const int wave = tid >> 6;
  const int n = blockIdx.x * 4 + wave;

  __shared__ u16 h_bf[2][64][HBF_S];      // 18.4 KB (h, later h2)
  __shared__ u16 q_s[4][64][QKS2];        // 12.3 KB
  __shared__ u16 k_s[4][64][QKS2];        // 12.3 KB
  __shared__ float xnh_s[64];
  __shared__ float svx_s[4][16][4];
  __shared__ float mred[4][64];

  // ---- phase 1: load ----
  const float* hb = h_in + (size_t)n * (NH_*MD_);
  float hr[16];
  #pragma unroll
  for (int i = 0; i < 16; ++i) {
    hr[i] = hb[i*64 + lane];
    u16 hi16 = f2bf(hr[i]);
    h_bf[0][wave*16 + i][lane] = hi16;
    h_bf[1][wave*16 + i][lane] = f2bf(hr[i] - bf2f(hi16));
  }
  if (tid < 64) xnh_s[tid] = xnh[(size_t)blockIdx.x * 64 + tid];

  // wvo_h[m=lane] = sum_d v_w[h*16+d] * out_w[(h*16+d)*64 + lane]
  float wvo[4];
  #pragma unroll
  for (int h = 0; h < 4; ++h) {
    float a = 0.f;
    for (int d = 0; d < 16; ++d)
      a = fmaf(v_w[h*16+d], out_w[(size_t)(h*16+d)*64 + lane], a);
    wvo[h] = a;
  }
  __syncthreads();

  // ---- phase 2: q/k MFMA. wave computes q cols wave*16..+15, k cols 64+wave*16..+15
  const int fr = lane & 15, fq = lane >> 4;
  {
    short8 bqh[2], bql[2], bkh[2], bkl[2];
    #pragma unroll
    for (int ks = 0; ks < 2; ++ks) {
      const int qcol = wave*16 + fr, kcol = 64 + wave*16 + fr;
      const int ko = ks*32 + fq*8;
      bqh[ks] = *(const short8*)&qkwt_hi[qcol*64 + ko];
      bql[ks] = *(const short8*)&qkwt_lo[qcol*64 + ko];
      bkh[ks] = *(const short8*)&qkwt_hi[kcol*64 + ko];
      bkl[ks] = *(const short8*)&qkwt_lo[kcol*64 + ko];
    }
    f32x4 accq[4], acck[4];
    #pragma unroll
    for (int mf = 0; mf < 4; ++mf) { accq[mf] = (f32x4){0,0,0,0}; acck[mf] = (f32x4){0,0,0,0}; }
    #pragma unroll
    for (int ks = 0; ks < 2; ++ks) {
      #pragma unroll
      for (int mf = 0; mf < 4; ++mf) {
        short8 ah = *(const short8*)&h_bf[0][mf*16 + fr][ks*32 + fq*8];
        short8 al = *(const short8*)&h_bf[1][mf*16 + fr][ks*32 + fq*8];
        accq[mf] = __builtin_amdgcn_mfma_f32_16x16x32_bf16(ah, bqh[ks], accq[mf], 0,0,0);
        accq[mf] = __builtin_amdgcn_mfma_f32_16x16x32_bf16(ah, bql[ks], accq[mf], 0,0,0);
        accq[mf] = __builtin_amdgcn_mfma_f32_16x16x32_bf16(al, bqh[ks], accq[mf], 0,0,0);
        acck[mf] = __builtin_amdgcn_mfma_f32_16x16x32_bf16(ah, bkh[ks], acck[mf], 0,0,0);
        acck[mf] = __builtin_amdgcn_mfma_f32_16x16x32_bf16(ah, bkl[ks], acck[mf], 0,0,0);
        acck[mf] = __builtin_amdgcn_mfma_f32_16x16x32_bf16(al, bkh[ks], acck[mf], 0,0,0);
      }
    }
    #pragma unroll
    for (int mf = 0; mf < 4; ++mf)
      #pragma unroll
      for (int r = 0; r < 4; ++r) {
        const int row = mf*16 + fq*4 + r;
        q_s[wave][row][fr] = f2bf(accq[mf][r]);
        k_s[wave][row][fr] = f2bf(acck[mf][r]);
      }
  }
  __syncthreads();

  // ---- phase 3: attention. lane = block row, head = wave ----
  {
    const int nl = lane >> 4, il = lane & 15;
    const float sc = expf(fminf(logit_scale[wave], 4.60517019f));
    float qv[16]; float qs = 0.f;
    short8 qp0 = *(const short8*)&q_s[wave][lane][0];
    short8 qp1 = *(const short8*)&q_s[wave][lane][8];
    #pragma unroll
    for (int d = 0; d < 8; ++d) {
      qv[d]   = bf2f((u16)qp0[d]);  qs = fmaf(qv[d],   qv[d],   qs);
      qv[8+d] = bf2f((u16)qp1[d]);  qs = fmaf(qv[8+d], qv[8+d], qs);
    }
    const float rq = 1.f / (sqrtf(qs) + 1e-12f);
    float lg[16];
    #pragma unroll
    for (int j = 0; j < 16; ++j) {
      short8 kp0 = *(const short8*)&k_s[wave][(lane & 48) + j][0];
      short8 kp1 = *(const short8*)&k_s[wave][(lane & 48) + j][8];
      float ks = 0.f, dt = 0.f;
      #pragma unroll
      for (int d = 0; d < 8; ++d) {
        float kv0 = bf2f((u16)kp0[d]);
        float kv1 = bf2f((u16)kp1[d]);
        ks = fmaf(kv0, kv0, ks); dt = fmaf(qv[d], kv0, dt);
        ks = fmaf(kv1, kv1, ks); dt = fmaf(qv[8+d], kv1, dt);
      }
      lg[j] = dt * rq * (1.f/(sqrtf(ks)+1e-12f)) * sc;
    }
    float mx = lg[0];
    #pragma unroll
    for (int j = 1; j < 16; ++j) mx = fmaxf(mx, lg[j]);
    float se = 0.f, sx = 0.f;
    #pragma unroll
    for (int j = 0; j < 16; ++j) {
      float e = __expf(lg[j] - mx);
      se += e;
      sx = fmaf(e, xnh_s[(lane & 48) + j], sx);
    }
    svx_s[nl][il][wave] = sx / se;
  }
  __syncthreads();

  // ---- phase 4: factorized out-proj + residual + LN2 (lane = channel) ----
  const float ob = out_b[lane], g2 = ln2_g[lane], bb2 = ln2_b[lane];
  float h2[16];
  #pragma unroll
  for (int i = 0; i < 16; ++i) {
    float o = ob;
    #pragma unroll
    for (int h = 0; h < 4; ++h) o = fmaf(svx_s[wave][i][h], wvo[h], o);
    float t = hr[i] + o;
    float mu = wsum64(t) * (1.f/64.f);
    float d = t - mu;
    float var = wsum64(d*d) * (1.f/64.f);
    h2[i] = d * rsqrtf(var + 1e-5f) * g2 + bb2;
  }
  #pragma unroll
  for (int i = 0; i < 16; ++i) {
    u16 hi16 = f2bf(h2[i]);
    h_bf[0][wave*16 + i][lane] = hi16;
    h_bf[1][wave*16 + i][lane] = f2bf(h2[i] - bf2f(hi16));
  }
  __syncthreads();

  // ---- phase 5: nh layer-1 MFMA (wave cols wave*32..+31) + fused dot(nh_w2) ----
  {
    short8 bnh[2][2], bnl[2][2];   // [cf][ks]
    float b1v[2], w2v[2];
    #pragma unroll
    for (int cf = 0; cf < 2; ++cf) {
      const int col = wave*32 + cf*16 + fr;
      b1v[cf] = nh_b1[col];
      w2v[cf] = nh_w2[col];
      #pragma unroll
      for (int ks = 0; ks < 2; ++ks) {
        bnh[cf][ks] = *(const short8*)&nhw1t_hi[col*64 + ks*32 + fq*8];
        bnl[cf][ks] = *(const short8*)&nhw1t_lo[col*64 + ks*32 + fq*8];
      }
    }
    f32x4 accm[4][2];
    #pragma unroll
    for (int mf = 0; mf < 4; ++mf)
      #pragma unroll
      for (int cf = 0; cf < 2; ++cf) accm[mf][cf] = (f32x4){0,0,0,0};
    #pragma unroll
    for (int ks = 0; ks < 2; ++ks) {
      #pragma unroll
      for (int mf = 0; mf < 4; ++mf) {
        short8 ah = *(const short8*)&h_bf[0][mf*16 + fr][ks*32 + fq*8];
        short8 al = *(const short8*)&h_bf[1][mf*16 + fr][ks*32 + fq*8];
        #pragma unroll
        for (int cf = 0; cf < 2; ++cf) {
          accm[mf][cf] = __builtin_amdgcn_mfma_f32_16x16x32_bf16(ah, bnh[cf][ks], accm[mf][cf], 0,0,0);
          accm[mf][cf] = __builtin_amdgcn_mfma_f32_16x16x32_bf16(ah, bnl[cf][ks], accm[mf][cf], 0,0,0);
          accm[mf][cf] = __builtin_amdgcn_mfma_f32_16x16x32_bf16(al, bnh[cf][ks], accm[mf][cf], 0,0,0);
        }
      }
    }
    #pragma unroll
    for (int mf = 0; mf < 4; ++mf)
      #pragma unroll
      for (int r = 0; r < 4; ++r) {
        float p = leaky_(accm[mf][0][r] + b1v[0]) * w2v[0]
                + leaky_(accm[mf][1][r] + b1v[1]) * w2v[1];
        #pragma unroll
        for (int off = 1; off < 16; off <<= 1) p += __shfl_xor(p, off, 64);
        if (fr == 0) mred[wave][mf*16 + fq*4 + r] = p;
      }
  }
  __syncthreads();

  // ---- phase 6: m broadcast + residual + LN3 -> hu ----
  const float nb2 = nh_b2[0];
  float s1 = 0.f, s2 = 0.f;
  #pragma unroll
  for (int i = 0; i < 16; ++i) {
    float sm = mred[0][wave*16+i] + mred[1][wave*16+i]
             + mred[2][wave*16+i] + mred[3][wave*16+i];
    float mi = leaky_(sm + nb2);
    float v3 = h2[i] + mi;
    hr[i] = v3;                      // reuse hr as h3
    s1 += v3; s2 = fmaf(v3, v3, s2);
  }
  s1 = wsum64(s1); s2 = wsum64(s2);
  float mu = s1 * (1.f/1024.f);
  float var = s2 * (1.f/1024.f) - mu*mu;
  float rs = rsqrtf(var + 1e-5f);
  const size_t base = (size_t)n * 1024;
  #pragma unroll
  for (int i = 0; i < 16; ++i) {
    int cch = i*64 + lane;
    float v = (hr[i] - mu) * rs * ln3_g[cch] + ln3_b[cch];
    u16 hi16 = f2bf(v);
    hu_hi[base + cch] = hi16;
    hu_lo[base + cch] = f2bf(v - bf2f(hi16));
  }
}

// ---------------------------------------------------------------------------
// K0: uf weight split+transpose: W[K][N] fp32 -> Wt_hi/Wt_lo [N][K] bf16.
// ---------------------------------------------------------------------------
__global__ __launch_bounds__(256) void k0_wsplit(
    const float* __restrict__ W1, const float* __restrict__ W2,
    u16* __restrict__ T1h, u16* __restrict__ T1l,
    u16* __restrict__ T2h, u16* __restrict__ T2l) {
  __shared__ float t[64][65];
  const float* W = blockIdx.z ? W2 : W1;
  u16* Th = blockIdx.z ? T2h : T1h;
  u16* Tl = blockIdx.z ? T2l : T1l;
  const int bx = blockIdx.x * 64, by = blockIdx.y * 64;
  for (int i = threadIdx.x; i < 64*64; i += 256) {
    int r = i >> 6, c = i & 63;
    t[r][c] = W[(size_t)(bx + r) * 1024 + by + c];
  }
  __syncthreads();
  for (int i = threadIdx.x; i < 64*64; i += 256) {
    int r2 = i >> 6, c2 = i & 63;
    float v = t[c2][r2];
    u16 hi = f2bf(v);
    size_t o = (size_t)(by + r2) * 1024 + bx + c2;
    Th[o] = hi;
    Tl[o] = f2bf(v - bf2f(hi));
  }
}

// ---------------------------------------------------------------------------
// K0b: small-weight split+transpose for k3's MFMA phases.
// qkwt[col][k]: col 0-63 = q_w[:,col], 64-127 = k_w[:,col-64]. nhw1t[col][k].
// ---------------------------------------------------------------------------
__global__ __launch_bounds__(256) void k0b_wsplit2(
    const float* __restrict__ q_w, const float* __restrict__ k_w,
    const float* __restrict__ nh_w1,
    u16* __restrict__ qkwt_hi, u16* __restrict__ qkwt_lo,
    u16* __restrict__ nhw1t_hi, u16* __restrict__ nhw1t_lo) {
  int idx = blockIdx.x * 256 + threadIdx.x;   // 0 .. 16383
  int e = idx & 8191;
  int col = e >> 6, kk = e & 63;
  if (idx < 8192) {
    float v = (col < 64) ? q_w[kk*64 + col] : k_w[kk*64 + (col - 64)];
    u16 hi = f2bf(v);
    qkwt_hi[col*64 + kk] = hi;
    qkwt_lo[col*64 + kk] = f2bf(v - bf2f(hi));
  } else {
    float v = nh_w1[kk*128 + col];
    u16 hi = f2bf(v);
    nhw1t_hi[col*64 + kk] = hi;
    nhw1t_lo[col*64 + kk] = f2bf(v - bf2f(hi));
  }
}

// ---------------------------------------------------------------------------
// K5: split-bf16 MFMA GEMM. (unchanged, verified)
// ---------------------------------------------------------------------------
template<int OUT_BF16>
__global__ __launch_bounds__(256, 2) void k5_gemm(
    const u16* __restrict__ Ah, const u16* __restrict__ Al,
    const u16* __restrict__ Bth, const u16* __restrict__ Btl,
    const float* __restrict__ bias,
    u16* __restrict__ Chi, u16* __restrict__ Clo, float* __restrict__ Cf) {
  __shared__ u16 As[2][128*32];
  __shared__ u16 Bs[2][128*32];
  const int tid = threadIdx.x;
  const int lane = tid & 63;
  const int wave = tid >> 6;
  const int wr = (wave >> 1) * 64, wc = (wave & 1) * 64;
  const int mt = (int)blockIdx.x >> 3, nt = (int)blockIdx.x & 7;
  const int m0 = mt * 128, n0 = nt * 128;

  const int sr = tid >> 2, sk = (tid & 3) * 8;
  const size_t a_off = (size_t)(m0 + sr) * 1024 + sk;
  const size_t b_off = (size_t)(n0 + sr) * 1024 + sk;
  u16* lAh = &As[0][0] + tid * 8;
  u16* lAl = &As[1][0] + tid * 8;
  u16* lBh = &Bs[0][0] + tid * 8;
  u16* lBl = &Bs[1][0] + tid * 8;

  f32x4 acc[4][4];
  #pragma unroll
  for (int i = 0; i < 4; ++i)
    #pragma unroll
    for (int j = 0; j < 4; ++j) acc[i][j] = (f32x4){0.f, 0.f, 0.f, 0.f};

  const int fr = lane & 15, fq = lane >> 4;
  const int aoff = (wr + fr) * 32 + fq * 8;
  const int boff = (wc + fr) * 32 + fq * 8;

  for (int k0 = 0; k0 < 1024; k0 += 32) {
    __syncthreads();
    gload16(Ah  + a_off + k0,             lAh);
    gload16(Ah  + a_off + k0 + 64*1024,   lAh + 64*32);
    gload16(Al  + a_off + k0,             lAl);
    gload16(Al  + a_off + k0 + 64*1024,   lAl + 64*32);
    gload16(Bth + b_off + k0,             lBh);
    gload16(Bth + b_off + k0 + 64*1024,   lBh + 64*32);
    gload16(Btl + b_off + k0,             lBl);
    gload16(Btl + b_off + k0 + 64*1024,   lBl + 64*32);
    __syncthreads();

    short8 ah[4], al[4], bh[4], bl[4];
    #pragma unroll
    for (int i = 0; i < 4; ++i) {
      ah[i] = *(const short8*)&As[0][aoff + i*16*32];
      al[i] = *(const short8*)&As[1][aoff + i*16*32];
      bh[i] = *(const short8*)&Bs[0][boff + i*16*32];
      bl[i] = *(const short8*)&Bs[1][boff + i*16*32];
    }
    #pragma unroll
    for (int mi = 0; mi < 4; ++mi)
      #pragma unroll
      for (int ni = 0; ni < 4; ++ni) {
        acc[mi][ni] = __builtin_amdgcn_mfma_f32_16x16x32_bf16(ah[mi], bh[ni], acc[mi][ni], 0, 0, 0);
        acc[mi][ni] = __builtin_amdgcn_mfma_f32_16x16x32_bf16(ah[mi], bl[ni], acc[mi][ni], 0, 0, 0);
        acc[mi][ni] = __builtin_amdgcn_mfma_f32_16x16x32_bf16(al[mi], bh[ni], acc[mi][ni], 0, 0, 0);
      }
  }

  #pragma unroll
  for (int mi = 0; mi < 4; ++mi)
    #pragma unroll
    for (int ni = 0; ni < 4; ++ni) {
      const int col = n0 + wc + ni*16 + fr;
      const float bv = bias[col];
      #pragma unroll
      for (int r = 0; r < 4; ++r) {
        const int row = m0 + wr + mi*16 + fq*4 + r;
        float v = leaky_(acc[mi][ni][r] + bv);
        if (OUT_BF16) {
          u16 hi = f2bf(v);
          Chi[(size_t)row*1024 + col] = hi;
          Clo[(size_t)row*1024 + col] = f2bf(v - bf2f(hi));
        } else {
          Cf[(size_t)row*1024 + col] = v;
        }
      }
    }
}

// ---------------------------------------------------------------------------
extern "C" void kernel_launch(void* const* d_in, const int* in_sizes, int n_in,
                              void* d_out, int out_size, void* d_ws, size_t ws_size,
                              hipStream_t stream) {
  (void)in_sizes; (void)n_in; (void)out_size; (void)ws_size;
  const float* x     = (const float*)d_in[0];
  const float* ct    = (const float*)d_in[1];
  const float* cs    = (const float*)d_in[2];
  const float* pe_w1 = (const float*)d_in[3];
  const float* pe_b1 = (const float*)d_in[4];
  const float* pe_w2 = (const float*)d_in[5];
  const float* pe_b2 = (const float*)d_in[6];
  const float* q_w   = (const float*)d_in[7];
  const float* k_w   = (const float*)d_in[8];
  const float* v_w   = (const float*)d_in[9];
  const float* lsc   = (const float*)d_in[10];
  const float* out_w = (const float*)d_in[11];
  const float* out_b = (const float*)d_in[12];
  const float* nh_w1 = (const float*)d_in[13];
  const float* nh_b1 = (const float*)d_in[14];
  const float* nh_w2 = (const float*)d_in[15];
  const float* nh_b2 = (const float*)d_in[16];
  const float* uf_w1 = (const float*)d_in[17];
  const float* uf_b1 = (const float*)d_in[18];
  const float* uf_w2 = (const float*)d_in[19];
  const float* uf_b2 = (const float*)d_in[20];
  const float* ln1_g = (const float*)d_in[21];
  const float* ln1_b = (const float*)d_in[22];
  const float* ln2_g = (const float*)d_in[23];
  const float* ln2_b = (const float*)d_in[24];
  const float* ln3_g = (const float*)d_in[25];
  const float* ln3_b = (const float*)d_in[26];

  float* ws  = (float*)d_ws;
  float* xnh = ws;                                  // 131072 f
  float* rel = ws + 131072;                         // 262144 f
  float* h   = ws + 393216;                         // 8388608 f; dead after k3 -> mid hi/lo
  u16*  hu_hi = (u16*)(ws + 393216 + 8388608);      // 8388608 u16
  u16*  hu_lo = hu_hi + 8388608;                    // 8388608 u16
  u16*  wbase = (u16*)(ws + 393216 + 2*8388608);
  u16*  w1t_hi = wbase;                             // 1048576 u16 each
  u16*  w1t_lo = wbase + 1048576;
  u16*  w2t_hi = wbase + 2*1048576;
  u16*  w2t_lo = wbase + 3*1048576;
  u16*  qkwt_hi  = wbase + 4*1048576;               // 8192 u16 each
  u16*  qkwt_lo  = qkwt_hi + 8192;
  u16*  nhw1t_hi = qkwt_hi + 16384;
  u16*  nhw1t_lo = qkwt_hi + 24576;
  u16*  mid_hi = (u16*)h;                           // alias: h dead after k3
  u16*  mid_lo = mid_hi + 8388608;
  float* out = (float*)d_out;

  k0_wsplit<<<dim3(16, 16, 2), dim3(256), 0, stream>>>(uf_w1, uf_w2,
                                                       w1t_hi, w1t_lo, w2t_hi, w2t_lo);
  k0b_wsplit2<<<dim3(64), dim3(256), 0, stream>>>(q_w, k_w, nh_w1,
                                                  qkwt_hi, qkwt_lo, nhw1t_hi, nhw1t_lo);
  k1_knn<<<dim3(BT_/4), dim3(256), 0, stream>>>(ct, cs, x, xnh, rel);
  k2_pe<<<dim3(BT_*NH_/16), dim3(256), 0, stream>>>(rel, xnh, pe_w1, pe_b1, pe_w2, pe_b2,
                                                    ln1_g, ln1_b, h);
  k3_attn<<<dim3(BT_/4), dim3(256), 0, stream>>>(h, xnh, qkwt_hi, qkwt_lo,
                                                 nhw1t_hi, nhw1t_lo,
                                                 v_w, lsc, out_w, out_b,
                                                 nh_b1, nh_w2, nh_b2,
                                                 ln2_g, ln2_b, ln3_g, ln3_b, hu_hi, hu_lo);
  k5_gemm<1><<<dim3(512), dim3(256), 0, stream>>>(hu_hi, hu_lo, w1t_hi, w1t_lo, uf_b1,
                                                  mid_hi, mid_lo, nullptr);
  k5_gemm<0><<<dim3(512), dim3(256), 0, stream>>>(mid_hi, mid_lo, w2t_hi, w2t_lo, uf_b2,
                                                  nullptr, nullptr, out);
}

// Round 7
// 428.332 us; speedup vs baseline: 2.0229x; 1.0890x over previous
//
#include <hip/hip_runtime.h>
#include <math.h>

#define B_ 2
#define T_ 4096
#define S_ 4096
#define NH_ 16
#define MD_ 64
#define FF_ 128
#define H_ 4
#define HD_ 16
#define BT_ (B_*T_)

typedef unsigned short u16;
typedef unsigned int u32;
typedef unsigned long long u64;
typedef __attribute__((ext_vector_type(8))) short short8;   // 8 bf16 (4 VGPRs)
typedef __attribute__((ext_vector_type(4))) float f32x4;

__device__ __forceinline__ float wsum64(float v) {
  #pragma unroll
  for (int off = 32; off > 0; off >>= 1) v += __shfl_xor(v, off, 64);
  return v;
}
__device__ __forceinline__ float leaky_(float x) { return x >= 0.f ? x : 0.2f * x; }
__device__ __forceinline__ u16 f2bf(float f) {            // RNE fp32 -> bf16
  u32 u = __float_as_uint(f);
  return (u16)((u + 0x7fffu + ((u >> 16) & 1u)) >> 16);
}
__device__ __forceinline__ float bf2f(u16 h) { return __uint_as_float((u32)h << 16); }

__device__ __forceinline__ void gload16(const void* g, void* l) {
  __builtin_amdgcn_global_load_lds(
      (const __attribute__((address_space(1))) u32*)g,
      (__attribute__((address_space(3))) u32*)l, 16, 0, 0);
}

__device__ __forceinline__ float dist2_(float2 c, float ctx, float cty) {
  float dx = ctx - c.x, dy = cty - c.y;
  return dx * dx + dy * dy;
}

// ---------------------------------------------------------------------------
// K1: kNN via two-pass threshold filter. (unchanged, verified)
// ---------------------------------------------------------------------------
__global__ __launch_bounds__(256) void k1_knn(
    const float* __restrict__ coords_target, const float* __restrict__ coords_source,
    const float* __restrict__ x, float* __restrict__ xnh, float* __restrict__ rel) {
  __shared__ float2 cs_s[S_];
  __shared__ u64 buf[4][128];
  const int tid = threadIdx.x;
  const int lane = tid & 63;
  const int wave = tid >> 6;
  const int n = blockIdx.x * 4 + wave;
  const int b = n >> 12;
  const float2* cs = (const float2*)coords_source + (size_t)b * S_;
  for (int i = tid; i < S_; i += 256) cs_s[i] = cs[i];
  __syncthreads();

  const float ctx = coords_target[n*2+0], cty = coords_target[n*2+1];

  float lmin = INFINITY;
  for (int kk = 0; kk < 64; ++kk)
    lmin = fminf(lmin, dist2_(cs_s[(kk << 6) | lane], ctx, cty));

  float v = lmin;
  #pragma unroll
  for (int k = 2; k <= 64; k <<= 1) {
    #pragma unroll
    for (int j = k >> 1; j > 0; j >>= 1) {
      float o = __shfl_xor(v, j, 64);
      bool keepmin = (((lane & j) == 0) == ((lane & k) == 0));
      v = keepmin ? fminf(v, o) : fmaxf(v, o);
    }
  }
  const float tau = __shfl(v, 15, 64);

  u64* wbuf = buf[wave];
  int cnt = 0;
  for (int kk = 0; kk < 64; ++kk) {
    int s = (kk << 6) | lane;
    float d2 = dist2_(cs_s[s], ctx, cty);
    bool q = (d2 <= tau);
    u64 mask = __ballot(q);
    if (q) {
      int pos = cnt + __popcll(mask & ((1ull << lane) - 1ull));
      if (pos < 128)
        wbuf[pos] = ((u64)__float_as_uint(d2) << 32) | (u32)s;
    }
    cnt += (int)__popcll(mask);
  }

  int myidx = 0;
  if (cnt >= 16 && cnt <= 128) {
    u64 c0 = (lane < cnt) ? wbuf[lane] : ~0ull;
    u64 c1 = (lane + 64 < cnt) ? wbuf[lane + 64] : ~0ull;
    for (int r = 0; r < 16; ++r) {
      u64 m = c0 < c1 ? c0 : c1;
      #pragma unroll
      for (int off = 32; off > 0; off >>= 1) {
        u64 o = __shfl_xor(m, off, 64);
        m = o < m ? o : m;
      }
      if (lane == r) myidx = (int)(u32)(m & 0xffffffffu);
      if (c0 == m) c0 = ~0ull;
      else if (c1 == m) c1 = ~0ull;
    }
  } else {
    float kd[16]; int ki[16];
    #pragma unroll
    for (int j = 0; j < 16; ++j) { kd[j] = INFINITY; ki[j] = 0x7fffffff; }
    for (int kk = 0; kk < 64; ++kk) {
      int s = (kk << 6) | lane;
      float d2 = dist2_(cs_s[s], ctx, cty);
      if (d2 < kd[15]) {
        float cd = d2; int ci = s;
        #pragma unroll
        for (int j = 0; j < 16; ++j) {
          bool sw = cd < kd[j];
          float td = sw ? kd[j] : cd;  int ti = sw ? ki[j] : ci;
          kd[j]    = sw ? cd : kd[j];  ki[j]    = sw ? ci : ki[j];
          cd = td; ci = ti;
        }
      }
    }
    for (int r = 0; r < 16; ++r) {
      float hd = kd[0]; int hi = ki[0];
      #pragma unroll
      for (int off = 32; off > 0; off >>= 1) {
        float od = __shfl_xor(hd, off, 64); int oi = __shfl_xor(hi, off, 64);
        bool take = (od < hd) || (od == hd && oi < hi);
        hd = take ? od : hd; hi = take ? oi : hi;
      }
      if (kd[0] == hd && ki[0] == hi) {
        #pragma unroll
        for (int j = 0; j < 15; ++j) { kd[j] = kd[j+1]; ki[j] = ki[j+1]; }
        kd[15] = INFINITY; ki[15] = 0x7fffffff;
      }
      if (lane == r) myidx = hi;
    }
  }

  if (lane < 16) {
    float2 c = cs_s[myidx];
    xnh[(size_t)n*NH_ + lane] = x[(size_t)b*S_ + myidx];
    rel[((size_t)n*NH_ + lane)*2 + 0] = c.x - ctx;
    rel[((size_t)n*NH_ + lane)*2 + 1] = c.y - cty;
  }
}

// ---------------------------------------------------------------------------
// K3: fully-fused block: pe-MLP + LN1 + q/k + attention + out-proj + LN2 +
// nh-MLP + LN3, all per (b,t)-group of 4. k2 is absorbed as phase 0.
// smem blob carving (45.8 KB, 3 blocks/CU):
//   h_bf  [2][64][72]  u16  (LN1 output h, later h2)       18432 B
//   qk    region 12288 u16: q_s/k_s [4][64][24] in ph2-3;  24576 B
//         aliased as hid [2][64][72] during phase 0
//   misc floats: xnh_s[64], svx[4][16][4], mred[4][64], c_s[4][32]
// ---------------------------------------------------------------------------
#define HBF_S 72   // row stride in u16 (144 B)
#define QKS2 24    // q_s/k_s row stride in u16 (48 B)
__global__ __launch_bounds__(256) void k3_attn(
    const float* __restrict__ rel, const float* __restrict__ xnh,
    const float* __restrict__ pe_w1, const float* __restrict__ pe_b1,
    const u16* __restrict__ pew2t_hi, const u16* __restrict__ pew2t_lo,
    const float* __restrict__ pe_b2,
    const float* __restrict__ ln1_g, const float* __restrict__ ln1_b,
    const u16* __restrict__ qkwt_hi, const u16* __restrict__ qkwt_lo,
    const u16* __restrict__ nhw1t_hi, const u16* __restrict__ nhw1t_lo,
    const float* __restrict__ v_w, const float* __restrict__ logit_scale,
    const float* __restrict__ out_w, const float* __restrict__ out_b,
    const float* __restrict__ nh_b1, const float* __restrict__ nh_w2,
    const float* __restrict__ nh_b2,
    const float* __restrict__ ln2_g, const float* __restrict__ ln2_b,
    const float* __restrict__ ln3_g, const float* __restrict__ ln3_b,
    u16* __restrict__ hu_hi, u16* __restrict__ hu_lo) {
  const int tid = threadIdx.x;
  const int lane = tid & 63;
  const int wave = tid >> 6;
  const int n = blockIdx.x * 4 + wave;
  const int fr = lane & 15, fq = lane >> 4;

  __shared__ __align__(16) char smem[45824];
  u16* h_bf0 = (u16*)smem;                       // [64][HBF_S]
  u16* h_bf1 = h_bf0 + 64*HBF_S;
  u16* qkreg = h_bf1 + 64*HBF_S;                 // 12288 u16
  u16* q_sB  = qkreg;                            // [4][64][QKS2]
  u16* k_sB  = qkreg + 4*64*QKS2;
  u16* hid0  = qkreg;                            // alias (phase 0 only)
  u16* hid1  = qkreg + 64*HBF_S;
  float* fmisc = (float*)(qkreg + 8*64*QKS2);
  float* xnh_s = fmisc;                          // 64
  float* svx_s = fmisc + 64;                     // [4][16][4]
  float* mred  = fmisc + 64 + 256;               // [4][64]
  float* c_s   = fmisc + 64 + 256 + 256;         // [4][32]

  // ---- phase 0a: stage c-transform + xnh; compute wvo ----
  if (lane < 32) {
    float rv = rel[(size_t)blockIdx.x*128 + wave*32 + lane];
    float a = log1pf(fabsf(rv));
    c_s[wave*32 + lane] = rv > 0.f ? a : (rv < 0.f ? -a : 0.f);
  }
  if (tid < 64) xnh_s[tid] = xnh[(size_t)blockIdx.x*64 + tid];
  float wvo[4];
  #pragma unroll
  for (int h = 0; h < 4; ++h) {
    float a = 0.f;
    for (int d = 0; d < 16; ++d)
      a = fmaf(v_w[h*16+d], out_w[(size_t)(h*16+d)*64 + lane], a);
    wvo[h] = a;
  }
  __syncthreads();

  // ---- phase 0b: hidden (2->128 relu) in two 64-ch passes + pe MFMA ----
  f32x4 acc_pe[4];
  #pragma unroll
  for (int nf = 0; nf < 4; ++nf) acc_pe[nf] = (f32x4){0,0,0,0};
  for (int p = 0; p < 2; ++p) {
    const float w10 = pe_w1[p*64 + lane];
    const float w11 = pe_w1[128 + p*64 + lane];
    const float b1  = pe_b1[p*64 + lane];
    #pragma unroll
    for (int i = 0; i < 16; ++i) {
      float c0 = c_s[wave*32 + i*2], c1v = c_s[wave*32 + i*2 + 1];
      float hv = fmaxf(fmaf(c0, w10, fmaf(c1v, w11, b1)), 0.f);
      u16 hh = f2bf(hv);
      hid0[(wave*16+i)*HBF_S + lane] = hh;
      hid1[(wave*16+i)*HBF_S + lane] = f2bf(hv - bf2f(hh));
    }
    __syncthreads();
    #pragma unroll
    for (int ks = 0; ks < 2; ++ks) {
      short8 ah = *(const short8*)&hid0[(wave*16+fr)*HBF_S + ks*32 + fq*8];
      short8 al = *(const short8*)&hid1[(wave*16+fr)*HBF_S + ks*32 + fq*8];
      #pragma unroll
      for (int nf = 0; nf < 4; ++nf) {
        short8 bh = *(const short8*)&pew2t_hi[(nf*16+fr)*128 + p*64 + ks*32 + fq*8];
        short8 bl = *(const short8*)&pew2t_lo[(nf*16+fr)*128 + p*64 + ks*32 + fq*8];
        acc_pe[nf] = __builtin_amdgcn_mfma_f32_16x16x32_bf16(ah, bh, acc_pe[nf], 0,0,0);
        acc_pe[nf] = __builtin_amdgcn_mfma_f32_16x16x32_bf16(ah, bl, acc_pe[nf], 0,0,0);
        acc_pe[nf] = __builtin_amdgcn_mfma_f32_16x16x32_bf16(al, bh, acc_pe[nf], 0,0,0);
      }
    }
    __syncthreads();   // hid reads done before overwrite / before q_s reuse
  }

  // ---- phase 0c: +pe_b2 +xnh, LN1 (16-lane reduce), write h -> h_bf ----
  {
    float gv[4], bv[4], b2v[4];
    #pragma unroll
    for (int nf = 0; nf < 4; ++nf) {
      int ch = nf*16 + fr;
      gv[nf] = ln1_g[ch]; bv[nf] = ln1_b[ch]; b2v[nf] = pe_b2[ch];
    }
    #pragma unroll
    for (int r = 0; r < 4; ++r) {
      const int row = wave*16 + fq*4 + r;
      const float xv = xnh_s[row];
      float t[4];
      #pragma unroll
      for (int nf = 0; nf < 4; ++nf) t[nf] = acc_pe[nf][r] + b2v[nf] + xv;
      float ps = t[0]+t[1]+t[2]+t[3];
      #pragma unroll
      for (int off = 1; off < 16; off <<= 1) ps += __shfl_xor(ps, off, 64);
      float mu = ps * (1.f/64.f);
      float vs = 0.f;
      #pragma unroll
      for (int nf = 0; nf < 4; ++nf) { float d = t[nf]-mu; vs = fmaf(d,d,vs); }
      #pragma unroll
      for (int off = 1; off < 16; off <<= 1) vs += __shfl_xor(vs, off, 64);
      float rs = rsqrtf(vs*(1.f/64.f) + 1e-5f);
      #pragma unroll
      for (int nf = 0; nf < 4; ++nf) {
        int ch = nf*16 + fr;
        float hn = (t[nf]-mu)*rs*gv[nf] + bv[nf];
        u16 hh = f2bf(hn);
        h_bf0[row*HBF_S + ch] = hh;
        h_bf1[row*HBF_S + ch] = f2bf(hn - bf2f(hh));
      }
    }
  }
  __syncthreads();

  // ---- phase 2: q/k MFMA ----
  {
    short8 bqh[2], bql[2], bkh[2], bkl[2];
    #pragma unroll
    for (int ks = 0; ks < 2; ++ks) {
      const int qcol = wave*16 + fr, kcol = 64 + wave*16 + fr;
      const int ko = ks*32 + fq*8;
      bqh[ks] = *(const short8*)&qkwt_hi[qcol*64 + ko];
      bql[ks] = *(const short8*)&qkwt_lo[qcol*64 + ko];
      bkh[ks] = *(const short8*)&qkwt_hi[kcol*64 + ko];
      bkl[ks] = *(const short8*)&qkwt_lo[kcol*64 + ko];
    }
    f32x4 accq[4], acck[4];
    #pragma unroll
    for (int mf = 0; mf < 4; ++mf) { accq[mf] = (f32x4){0,0,0,0}; acck[mf] = (f32x4){0,0,0,0}; }
    #pragma unroll
    for (int ks = 0; ks < 2; ++ks) {
      #pragma unroll
      for (int mf = 0; mf < 4; ++mf) {
        short8 ah = *(const short8*)&h_bf0[(mf*16+fr)*HBF_S + ks*32 + fq*8];
        short8 al = *(const short8*)&h_bf1[(mf*16+fr)*HBF_S + ks*32 + fq*8];
        accq[mf] = __builtin_amdgcn_mfma_f32_16x16x32_bf16(ah, bqh[ks], accq[mf], 0,0,0);
        accq[mf] = __builtin_amdgcn_mfma_f32_16x16x32_bf16(ah, bql[ks], accq[mf], 0,0,0);
        accq[mf] = __builtin_amdgcn_mfma_f32_16x16x32_bf16(al, bqh[ks], accq[mf], 0,0,0);
        acck[mf] = __builtin_amdgcn_mfma_f32_16x16x32_bf16(ah, bkh[ks], acck[mf], 0,0,0);
        acck[mf] = __builtin_amdgcn_mfma_f32_16x16x32_bf16(ah, bkl[ks], acck[mf], 0,0,0);
        acck[mf] = __builtin_amdgcn_mfma_f32_16x16x32_bf16(al, bkh[ks], acck[mf], 0,0,0);
      }
    }
    #pragma unroll
    for (int mf = 0; mf < 4; ++mf)
      #pragma unroll
      for (int r = 0; r < 4; ++r) {
        const int row = mf*16 + fq*4 + r;
        q_sB[(wave*64+row)*QKS2 + fr] = f2bf(accq[mf][r]);
        k_sB[(wave*64+row)*QKS2 + fr] = f2bf(acck[mf][r]);
      }
  }
  __syncthreads();

  // ---- phase 3: attention. lane = block row, head = wave ----
  {
    const int nl = lane >> 4, il = lane & 15;
    const float sc = expf(fminf(logit_scale[wave], 4.60517019f));
    float qv[16]; float qs = 0.f;
    short8 qp0 = *(const short8*)&q_sB[(wave*64+lane)*QKS2 + 0];
    short8 qp1 = *(const short8*)&q_sB[(wave*64+lane)*QKS2 + 8];
    #pragma unroll
    for (int d = 0; d < 8; ++d) {
      qv[d]   = bf2f((u16)qp0[d]);  qs = fmaf(qv[d],   qv[d],   qs);
      qv[8+d] = bf2f((u16)qp1[d]);  qs = fmaf(qv[8+d], qv[8+d], qs);
    }
    const float rq = 1.f / (sqrtf(qs) + 1e-12f);
    float lg[16];
    #pragma unroll
    for (int j = 0; j < 16; ++j) {
      const int krow = (lane & 48) + j;
      short8 kp0 = *(const short8*)&k_sB[(wave*64+krow)*QKS2 + 0];
      short8 kp1 = *(const short8*)&k_sB[(wave*64+krow)*QKS2 + 8];
      float ks = 0.f, dt = 0.f;
      #pragma unroll
      for (int d = 0; d < 8; ++d) {
        float kv0 = bf2f((u16)kp0[d]);
        float kv1 = bf2f((u16)kp1[d]);
        ks = fmaf(kv0, kv0, ks); dt = fmaf(qv[d], kv0, dt);
        ks = fmaf(kv1, kv1, ks); dt = fmaf(qv[8+d], kv1, dt);
      }
      lg[j] = dt * rq * (1.f/(sqrtf(ks)+1e-12f)) * sc;
    }
    float mx = lg[0];
    #pragma unroll
    for (int j = 1; j < 16; ++j) mx = fmaxf(mx, lg[j]);
    float se = 0.f, sx = 0.f;
    #pragma unroll
    for (int j = 0; j < 16; ++j) {
      float e = __expf(lg[j] - mx);
      se += e;
      sx = fmaf(e, xnh_s[(lane & 48) + j], sx);
    }
    svx_s[(nl*16 + il)*4 + wave] = sx / se;
  }
  __syncthreads();

  // ---- phase 4: factorized out-proj + residual + LN2 (lane = channel) ----
  const float ob = out_b[lane], g2 = ln2_g[lane], bb2 = ln2_b[lane];
  float h2[16];
  #pragma unroll
  for (int i = 0; i < 16; ++i) {
    float hfull = bf2f(h_bf0[(wave*16+i)*HBF_S + lane])
                + bf2f(h_bf1[(wave*16+i)*HBF_S + lane]);
    float o = ob;
    #pragma unroll
    for (int h = 0; h < 4; ++h) o = fmaf(svx_s[(wave*16+i)*4 + h], wvo[h], o);
    float t = hfull + o;
    float mu = wsum64(t) * (1.f/64.f);
    float d = t - mu;
    float var = wsum64(d*d) * (1.f/64.f);
    h2[i] = d * rsqrtf(var + 1e-5f) * g2 + bb2;
    u16 hh = f2bf(h2[i]);
    h_bf0[(wave*16+i)*HBF_S + lane] = hh;
    h_bf1[(wave*16+i)*HBF_S + lane] = f2bf(h2[i] - bf2f(hh));
  }
  __syncthreads();

  // ---- phase 5: nh layer-1 MFMA + fused leaky+dot(nh_w2) + 16-lane reduce ----
  {
    short8 bnh[2][2], bnl[2][2];   // [cf][ks]
    float b1v[2], w2v[2];
    #pragma unroll
    for (int cf = 0; cf < 2; ++cf) {
      const int col = wave*32 + cf*16 + fr;
      b1v[cf] = nh_b1[col];
      w2v[cf] = nh_w2[col];
      #pragma unroll
      for (int ks = 0; ks < 2; ++ks) {
        bnh[cf][ks] = *(const short8*)&nhw1t_hi[col*64 + ks*32 + fq*8];
        bnl[cf][ks] = *(const short8*)&nhw1t_lo[col*64 + ks*32 + fq*8];
      }
    }
    f32x4 accm[4][2];
    #pragma unroll
    for (int mf = 0; mf < 4; ++mf)
      #pragma unroll
      for (int cf = 0; cf < 2; ++cf) accm[mf][cf] = (f32x4){0,0,0,0};
    #pragma unroll
    for (int ks = 0; ks < 2; ++ks) {
      #pragma unroll
      for (int mf = 0; mf < 4; ++mf) {
        short8 ah = *(const short8*)&h_bf0[(mf*16+fr)*HBF_S + ks*32 + fq*8];
        short8 al = *(const short8*)&h_bf1[(mf*16+fr)*HBF_S + ks*32 + fq*8];
        #pragma unroll
        for (int cf = 0; cf < 2; ++cf) {
          accm[mf][cf] = __builtin_amdgcn_mfma_f32_16x16x32_bf16(ah, bnh[cf][ks], accm[mf][cf], 0,0,0);
          accm[mf][cf] = __builtin_amdgcn_mfma_f32_16x16x32_bf16(ah, bnl[cf][ks], accm[mf][cf], 0,0,0);
          accm[mf][cf] = __builtin_amdgcn_mfma_f32_16x16x32_bf16(al, bnh[cf][ks], accm[mf][cf], 0,0,0);
        }
      }
    }
    #pragma unroll
    for (int mf = 0; mf < 4; ++mf)
      #pragma unroll
      for (int r = 0; r < 4; ++r) {
        float p = leaky_(accm[mf][0][r] + b1v[0]) * w2v[0]
                + leaky_(accm[mf][1][r] + b1v[1]) * w2v[1];
        #pragma unroll
        for (int off = 1; off < 16; off <<= 1) p += __shfl_xor(p, off, 64);
        if (fr == 0) mred[wave*64 + mf*16 + fq*4 + r] = p;
      }
  }
  __syncthreads();

  // ---- phase 6: m broadcast + residual + LN3 -> hu ----
  const float nb2 = nh_b2[0];
  float h3[16];
  float s1 = 0.f, s2 = 0.f;
  #pragma unroll
  for (int i = 0; i < 16; ++i) {
    float sm = mred[0*64 + wave*16+i] + mred[1*64 + wave*16+i]
             + mred[2*64 + wave*16+i] + mred[3*64 + wave*16+i];
    float mi = leaky_(sm + nb2);
    float v3 = h2[i] + mi;
    h3[i] = v3;
    s1 += v3; s2 = fmaf(v3, v3, s2);
  }
  s1 = wsum64(s1); s2 = wsum64(s2);
  float mu = s1 * (1.f/1024.f);
  float var = s2 * (1.f/1024.f) - mu*mu;
  float rs = rsqrtf(var + 1e-5f);
  const size_t base = (size_t)n * 1024;
  #pragma unroll
  for (int i = 0; i < 16; ++i) {
    int cch = i*64 + lane;
    float v = (h3[i] - mu) * rs * ln3_g[cch] + ln3_b[cch];
    u16 hi16 = f2bf(v);
    hu_hi[base + cch] = hi16;
    hu_lo[base + cch] = f2bf(v - bf2f(hi16));
  }
}

// ---------------------------------------------------------------------------
// K0: uf weight split+transpose: W[K][N] fp32 -> Wt_hi/Wt_lo [N][K] bf16.
// ---------------------------------------------------------------------------
__global__ __launch_bounds__(256) void k0_wsplit(
    const float* __restrict__ W1, const float* __restrict__ W2,
    u16* __restrict__ T1h, u16* __restrict__ T1l,
    u16* __restrict__ T2h, u16* __restrict__ T2l) {
  __shared__ float t[64][65];
  const float* W = blockIdx.z ? W2 : W1;
  u16* Th = blockIdx.z ? T2h : T1h;
  u16* Tl = blockIdx.z ? T2l : T1l;
  const int bx = blockIdx.x * 64, by = blockIdx.y * 64;
  for (int i = threadIdx.x; i < 64*64; i += 256) {
    int r = i >> 6, c = i & 63;
    t[r][c] = W[(size_t)(bx + r) * 1024 + by + c];
  }
  __syncthreads();
  for (int i = threadIdx.x; i < 64*64; i += 256) {
    int r2 = i >> 6, c2 = i & 63;
    float v = t[c2][r2];
    u16 hi = f2bf(v);
    size_t o = (size_t)(by + r2) * 1024 + bx + c2;
    Th[o] = hi;
    Tl[o] = f2bf(v - bf2f(hi));
  }
}

// ---------------------------------------------------------------------------
// K0b: small-weight split+transpose for k3's MFMA phases.
// [0,8192):   qkwt[col][k], col 0-63 = q_w[:,col], 64-127 = k_w[:,col-64]
// [8192,16384): nhw1t[col][k]  (nh_w1 is 64x128)
// [16384,24576): pew2t[col][j] (pe_w2 is 128x64)
// ---------------------------------------------------------------------------
__global__ __launch_bounds__(256) void k0b_wsplit2(
    const float* __restrict__ q_w, const float* __restrict__ k_w,
    const float* __restrict__ nh_w1, const float* __restrict__ pe_w2,
    u16* __restrict__ qkwt_hi, u16* __restrict__ qkwt_lo,
    u16* __restrict__ nhw1t_hi, u16* __restrict__ nhw1t_lo,
    u16* __restrict__ pew2t_hi, u16* __restrict__ pew2t_lo) {
  int idx = blockIdx.x * 256 + threadIdx.x;   // 0 .. 24575
  if (idx < 8192) {
    int col = idx >> 6, kk = idx & 63;
    float v = (col < 64) ? q_w[kk*64 + col] : k_w[kk*64 + (col - 64)];
    u16 hi = f2bf(v);
    qkwt_hi[col*64 + kk] = hi;
    qkwt_lo[col*64 + kk] = f2bf(v - bf2f(hi));
  } else if (idx < 16384) {
    int e = idx - 8192;
    int col = e >> 6, kk = e & 63;
    float v = nh_w1[kk*128 + col];
    u16 hi = f2bf(v);
    nhw1t_hi[col*64 + kk] = hi;
    nhw1t_lo[col*64 + kk] = f2bf(v - bf2f(hi));
  } else {
    int e = idx - 16384;
    int col = e >> 7, j = e & 127;
    float v = pe_w2[j*64 + col];
    u16 hi = f2bf(v);
    pew2t_hi[col*128 + j] = hi;
    pew2t_lo[col*128 + j] = f2bf(v - bf2f(hi));
  }
}

// ---------------------------------------------------------------------------
// K5: split-bf16 MFMA GEMM (verified). + XCD-aware block swizzle (512%8==0).
// ---------------------------------------------------------------------------
template<int OUT_BF16>
__global__ __launch_bounds__(256, 2) void k5_gemm(
    const u16* __restrict__ Ah, const u16* __restrict__ Al,
    const u16* __restrict__ Bth, const u16* __restrict__ Btl,
    const float* __restrict__ bias,
    u16* __restrict__ Chi, u16* __restrict__ Clo, float* __restrict__ Cf) {
  __shared__ u16 As[2][128*32];
  __shared__ u16 Bs[2][128*32];
  const int tid = threadIdx.x;
  const int lane = tid & 63;
  const int wave = tid >> 6;
  const int wr = (wave >> 1) * 64, wc = (wave & 1) * 64;
  const int bid = (int)blockIdx.x;
  const int swz = (bid & 7) * 64 + (bid >> 3);   // 8 XCDs x 64 contiguous tiles
  const int mt = swz >> 3, nt = swz & 7;
  const int m0 = mt * 128, n0 = nt * 128;

  const int sr = tid >> 2, sk = (tid & 3) * 8;
  const size_t a_off = (size_t)(m0 + sr) * 1024 + sk;
  const size_t b_off = (size_t)(n0 + sr) * 1024 + sk;
  u16* lAh = &As[0][0] + tid * 8;
  u16* lAl = &As[1][0] + tid * 8;
  u16* lBh = &Bs[0][0] + tid * 8;
  u16* lBl = &Bs[1][0] + tid * 8;

  f32x4 acc[4][4];
  #pragma unroll
  for (int i = 0; i < 4; ++i)
    #pragma unroll
    for (int j = 0; j < 4; ++j) acc[i][j] = (f32x4){0.f, 0.f, 0.f, 0.f};

  const int fr = lane & 15, fq = lane >> 4;
  const int aoff = (wr + fr) * 32 + fq * 8;
  const int boff = (wc + fr) * 32 + fq * 8;

  for (int k0 = 0; k0 < 1024; k0 += 32) {
    __syncthreads();
    gload16(Ah  + a_off + k0,             lAh);
    gload16(Ah  + a_off + k0 + 64*1024,   lAh + 64*32);
    gload16(Al  + a_off + k0,             lAl);
    gload16(Al  + a_off + k0 + 64*1024,   lAl + 64*32);
    gload16(Bth + b_off + k0,             lBh);
    gload16(Bth + b_off + k0 + 64*1024,   lBh + 64*32);
    gload16(Btl + b_off + k0,             lBl);
    gload16(Btl + b_off + k0 + 64*1024,   lBl + 64*32);
    __syncthreads();

    short8 ah[4], al[4], bh[4], bl[4];
    #pragma unroll
    for (int i = 0; i < 4; ++i) {
      ah[i] = *(const short8*)&As[0][aoff + i*16*32];
      al[i] = *(const short8*)&As[1][aoff + i*16*32];
      bh[i] = *(const short8*)&Bs[0][boff + i*16*32];
      bl[i] = *(const short8*)&Bs[1][boff + i*16*32];
    }
    #pragma unroll
    for (int mi = 0; mi < 4; ++mi)
      #pragma unroll
      for (int ni = 0; ni < 4; ++ni) {
        acc[mi][ni] = __builtin_amdgcn_mfma_f32_16x16x32_bf16(ah[mi], bh[ni], acc[mi][ni], 0, 0, 0);
        acc[mi][ni] = __builtin_amdgcn_mfma_f32_16x16x32_bf16(ah[mi], bl[ni], acc[mi][ni], 0, 0, 0);
        acc[mi][ni] = __builtin_amdgcn_mfma_f32_16x16x32_bf16(al[mi], bh[ni], acc[mi][ni], 0, 0, 0);
      }
  }

  #pragma unroll
  for (int mi = 0; mi < 4; ++mi)
    #pragma unroll
    for (int ni = 0; ni < 4; ++ni) {
      const int col = n0 + wc + ni*16 + fr;
      const float bv = bias[col];
      #pragma unroll
      for (int r = 0; r < 4; ++r) {
        const int row = m0 + wr + mi*16 + fq*4 + r;
        float v = leaky_(acc[mi][ni][r] + bv);
        if (OUT_BF16) {
          u16 hi = f2bf(v);
          Chi[(size_t)row*1024 + col] = hi;
          Clo[(size_t)row*1024 + col] = f2bf(v - bf2f(hi));
        } else {
          Cf[(size_t)row*1024 + col] = v;
        }
      }
    }
}

// ---------------------------------------------------------------------------
extern "C" void kernel_launch(void* const* d_in, const int* in_sizes, int n_in,
                              void* d_out, int out_size, void* d_ws, size_t ws_size,
                              hipStream_t stream) {
  (void)in_sizes; (void)n_in; (void)out_size; (void)ws_size;
  const float* x     = (const float*)d_in[0];
  const float* ct    = (const float*)d_in[1];
  const float* cs    = (const float*)d_in[2];
  const float* pe_w1 = (const float*)d_in[3];
  const float* pe_b1 = (const float*)d_in[4];
  const float* pe_w2 = (const float*)d_in[5];
  const float* pe_b2 = (const float*)d_in[6];
  const float* q_w   = (const float*)d_in[7];
  const float* k_w   = (const float*)d_in[8];
  const float* v_w   = (const float*)d_in[9];
  const float* lsc   = (const float*)d_in[10];
  const float* out_w = (const float*)d_in[11];
  const float* out_b = (const float*)d_in[12];
  const float* nh_w1 = (const float*)d_in[13];
  const float* nh_b1 = (const float*)d_in[14];
  const float* nh_w2 = (const float*)d_in[15];
  const float* nh_b2 = (const float*)d_in[16];
  const float* uf_w1 = (const float*)d_in[17];
  const float* uf_b1 = (const float*)d_in[18];
  const float* uf_w2 = (const float*)d_in[19];
  const float* uf_b2 = (const float*)d_in[20];
  const float* ln1_g = (const float*)d_in[21];
  const float* ln1_b = (const float*)d_in[22];
  const float* ln2_g = (const float*)d_in[23];
  const float* ln2_b = (const float*)d_in[24];
  const float* ln3_g = (const float*)d_in[25];
  const float* ln3_b = (const float*)d_in[26];

  float* ws  = (float*)d_ws;
  float* xnh = ws;                                  // 131072 f
  float* rel = ws + 131072;                         // 262144 f
  float* h   = ws + 393216;                         // 8388608 f (mid hi/lo alias)
  u16*  hu_hi = (u16*)(ws + 393216 + 8388608);      // 8388608 u16
  u16*  hu_lo = hu_hi + 8388608;                    // 8388608 u16
  u16*  wbase = (u16*)(ws + 393216 + 2*8388608);
  u16*  w1t_hi = wbase;                             // 1048576 u16 each
  u16*  w1t_lo = wbase + 1048576;
  u16*  w2t_hi = wbase + 2*1048576;
  u16*  w2t_lo = wbase + 3*1048576;
  u16*  qkwt_hi  = wbase + 4*1048576;               // 8192 u16 each
  u16*  qkwt_lo  = qkwt_hi + 8192;
  u16*  nhw1t_hi = qkwt_hi + 16384;
  u16*  nhw1t_lo = qkwt_hi + 24576;
  u16*  pew2t_hi = qkwt_hi + 32768;
  u16*  pew2t_lo = qkwt_hi + 40960;
  u16*  mid_hi = (u16*)h;
  u16*  mid_lo = mid_hi + 8388608;
  float* out = (float*)d_out;

  k0_wsplit<<<dim3(16, 16, 2), dim3(256), 0, stream>>>(uf_w1, uf_w2,
                                                       w1t_hi, w1t_lo, w2t_hi, w2t_lo);
  k0b_wsplit2<<<dim3(96), dim3(256), 0, stream>>>(q_w, k_w, nh_w1, pe_w2,
                                                  qkwt_hi, qkwt_lo, nhw1t_hi, nhw1t_lo,
                                                  pew2t_hi, pew2t_lo);
  k1_knn<<<dim3(BT_/4), dim3(256), 0, stream>>>(ct, cs, x, xnh, rel);
  k3_attn<<<dim3(BT_/4), dim3(256), 0, stream>>>(rel, xnh, pe_w1, pe_b1,
                                                 pew2t_hi, pew2t_lo, pe_b2,
                                                 ln1_g, ln1_b,
                                                 qkwt_hi, qkwt_lo, nhw1t_hi, nhw1t_lo,
                                                 v_w, lsc, out_w, out_b,
                                                 nh_b1, nh_w2, nh_b2,
                                                 ln2_g, ln2_b, ln3_g, ln3_b, hu_hi, hu_lo);
  k5_gemm<1><<<dim3(512), dim3(256), 0, stream>>>(hu_hi, hu_lo, w1t_hi, w1t_lo, uf_b1,
                                                  mid_hi, mid_lo, nullptr);
  k5_gemm<0><<<dim3(512), dim3(256), 0, stream>>>(mid_hi, mid_lo, w2t_hi, w2t_lo, uf_b2,
                                                  nullptr, nullptr, out);
}

// Round 8
// 414.411 us; speedup vs baseline: 2.0908x; 1.0336x over previous
//
#include <hip/hip_runtime.h>
#include <math.h>

#define B_ 2
#define T_ 4096
#define S_ 4096
#define NH_ 16
#define MD_ 64
#define FF_ 128
#define H_ 4
#define HD_ 16
#define BT_ (B_*T_)

typedef unsigned short u16;
typedef unsigned int u32;
typedef unsigned long long u64;
typedef __attribute__((ext_vector_type(8))) short short8;   // 8 bf16 (4 VGPRs)
typedef __attribute__((ext_vector_type(4))) float f32x4;

__device__ __forceinline__ float wsum64(float v) {
  #pragma unroll
  for (int off = 32; off > 0; off >>= 1) v += __shfl_xor(v, off, 64);
  return v;
}
__device__ __forceinline__ float leaky_(float x) { return x >= 0.f ? x : 0.2f * x; }
__device__ __forceinline__ u16 f2bf(float f) {            // RNE fp32 -> bf16
  u32 u = __float_as_uint(f);
  return (u16)((u + 0x7fffu + ((u >> 16) & 1u)) >> 16);
}
__device__ __forceinline__ float bf2f(u16 h) { return __uint_as_float((u32)h << 16); }

__device__ __forceinline__ void gload16(const void* g, void* l) {
  __builtin_amdgcn_global_load_lds(
      (const __attribute__((address_space(1))) u32*)g,
      (__attribute__((address_space(3))) u32*)l, 16, 0, 0);
}

__device__ __forceinline__ float dist2_(float2 c, float ctx, float cty) {
  float dx = ctx - c.x, dy = cty - c.y;
  return dx * dx + dy * dy;
}

// ---------------------------------------------------------------------------
// K1: kNN via two-pass threshold filter. (unchanged, verified)
// ---------------------------------------------------------------------------
__global__ __launch_bounds__(256) void k1_knn(
    const float* __restrict__ coords_target, const float* __restrict__ coords_source,
    const float* __restrict__ x, float* __restrict__ xnh, float* __restrict__ rel) {
  __shared__ float2 cs_s[S_];
  __shared__ u64 buf[4][128];
  const int tid = threadIdx.x;
  const int lane = tid & 63;
  const int wave = tid >> 6;
  const int n = blockIdx.x * 4 + wave;
  const int b = n >> 12;
  const float2* cs = (const float2*)coords_source + (size_t)b * S_;
  for (int i = tid; i < S_; i += 256) cs_s[i] = cs[i];
  __syncthreads();

  const float ctx = coords_target[n*2+0], cty = coords_target[n*2+1];

  float lmin = INFINITY;
  for (int kk = 0; kk < 64; ++kk)
    lmin = fminf(lmin, dist2_(cs_s[(kk << 6) | lane], ctx, cty));

  float v = lmin;
  #pragma unroll
  for (int k = 2; k <= 64; k <<= 1) {
    #pragma unroll
    for (int j = k >> 1; j > 0; j >>= 1) {
      float o = __shfl_xor(v, j, 64);
      bool keepmin = (((lane & j) == 0) == ((lane & k) == 0));
      v = keepmin ? fminf(v, o) : fmaxf(v, o);
    }
  }
  const float tau = __shfl(v, 15, 64);

  u64* wbuf = buf[wave];
  int cnt = 0;
  for (int kk = 0; kk < 64; ++kk) {
    int s = (kk << 6) | lane;
    float d2 = dist2_(cs_s[s], ctx, cty);
    bool q = (d2 <= tau);
    u64 mask = __ballot(q);
    if (q) {
      int pos = cnt + __popcll(mask & ((1ull << lane) - 1ull));
      if (pos < 128)
        wbuf[pos] = ((u64)__float_as_uint(d2) << 32) | (u32)s;
    }
    cnt += (int)__popcll(mask);
  }

  int myidx = 0;
  if (cnt >= 16 && cnt <= 128) {
    u64 c0 = (lane < cnt) ? wbuf[lane] : ~0ull;
    u64 c1 = (lane + 64 < cnt) ? wbuf[lane + 64] : ~0ull;
    for (int r = 0; r < 16; ++r) {
      u64 m = c0 < c1 ? c0 : c1;
      #pragma unroll
      for (int off = 32; off > 0; off >>= 1) {
        u64 o = __shfl_xor(m, off, 64);
        m = o < m ? o : m;
      }
      if (lane == r) myidx = (int)(u32)(m & 0xffffffffu);
      if (c0 == m) c0 = ~0ull;
      else if (c1 == m) c1 = ~0ull;
    }
  } else {
    float kd[16]; int ki[16];
    #pragma unroll
    for (int j = 0; j < 16; ++j) { kd[j] = INFINITY; ki[j] = 0x7fffffff; }
    for (int kk = 0; kk < 64; ++kk) {
      int s = (kk << 6) | lane;
      float d2 = dist2_(cs_s[s], ctx, cty);
      if (d2 < kd[15]) {
        float cd = d2; int ci = s;
        #pragma unroll
        for (int j = 0; j < 16; ++j) {
          bool sw = cd < kd[j];
          float td = sw ? kd[j] : cd;  int ti = sw ? ki[j] : ci;
          kd[j]    = sw ? cd : kd[j];  ki[j]    = sw ? ci : ki[j];
          cd = td; ci = ti;
        }
      }
    }
    for (int r = 0; r < 16; ++r) {
      float hd = kd[0]; int hi = ki[0];
      #pragma unroll
      for (int off = 32; off > 0; off >>= 1) {
        float od = __shfl_xor(hd, off, 64); int oi = __shfl_xor(hi, off, 64);
        bool take = (od < hd) || (od == hd && oi < hi);
        hd = take ? od : hd; hi = take ? oi : hi;
      }
      if (kd[0] == hd && ki[0] == hi) {
        #pragma unroll
        for (int j = 0; j < 15; ++j) { kd[j] = kd[j+1]; ki[j] = ki[j+1]; }
        kd[15] = INFINITY; ki[15] = 0x7fffffff;
      }
      if (lane == r) myidx = hi;
    }
  }

  if (lane < 16) {
    float2 c = cs_s[myidx];
    xnh[(size_t)n*NH_ + lane] = x[(size_t)b*S_ + myidx];
    rel[((size_t)n*NH_ + lane)*2 + 0] = c.x - ctx;
    rel[((size_t)n*NH_ + lane)*2 + 1] = c.y - cty;
  }
}

// ---------------------------------------------------------------------------
// K3: fully-fused block, latency-optimized:
//  - all in-kernel MFMAs 1-term plain bf16 (error paths attenuated by wvo /
//    0.02-scale weights; residual h/h2 kept hi/lo in LDS)
//  - 36.6 KB LDS -> 4 blocks/CU;  5 barriers (phase-private panels need none)
// smem carving (u16 elems):
//   h_bf0/h_bf1 [64][66]          (h, later h2; hi/lo)      2*4224 u16
//   qkhid region 8448 u16: hid [64][132] bf16 in phase 0;
//                          q_s/k_s [4][64][16] in phases 2-3
//   misc floats: xnh_s[64], svx[256], mred[256], c_s[128]   704 f
// ---------------------------------------------------------------------------
#define HBF_S 66    // h_bf row stride in u16 (132 B)
#define HID_S 132   // hid row stride in u16
#define QKS3 16     // q_s/k_s row stride in u16 (32 B)
__global__ __launch_bounds__(256) void k3_attn(
    const float* __restrict__ rel, const float* __restrict__ xnh,
    const float* __restrict__ pe_w1, const float* __restrict__ pe_b1,
    const u16* __restrict__ pew2t_hi, const u16* __restrict__ pew2t_lo,
    const float* __restrict__ pe_b2,
    const float* __restrict__ ln1_g, const float* __restrict__ ln1_b,
    const u16* __restrict__ qkwt_hi, const u16* __restrict__ qkwt_lo,
    const u16* __restrict__ nhw1t_hi, const u16* __restrict__ nhw1t_lo,
    const float* __restrict__ v_w, const float* __restrict__ logit_scale,
    const float* __restrict__ out_w, const float* __restrict__ out_b,
    const float* __restrict__ nh_b1, const float* __restrict__ nh_w2,
    const float* __restrict__ nh_b2,
    const float* __restrict__ ln2_g, const float* __restrict__ ln2_b,
    const float* __restrict__ ln3_g, const float* __restrict__ ln3_b,
    u16* __restrict__ hu_hi, u16* __restrict__ hu_lo) {
  (void)pew2t_lo; (void)qkwt_lo; (void)nhw1t_lo;
  const int tid = threadIdx.x;
  const int lane = tid & 63;
  const int wave = tid >> 6;
  const int n = blockIdx.x * 4 + wave;
  const int fr = lane & 15, fq = lane >> 4;

  __shared__ __align__(16) char smem[36608];
  u16* h_bf0 = (u16*)smem;                       // [64][HBF_S]
  u16* h_bf1 = h_bf0 + 64*HBF_S;
  u16* qkhid = h_bf1 + 64*HBF_S;                 // 8448 u16 region
  u16* hid   = qkhid;                            // [64][HID_S] (phase 0)
  u16* q_sB  = qkhid;                            // [4][64][QKS3] (phase 2+)
  u16* k_sB  = qkhid + 4*64*QKS3;
  float* fmisc = (float*)(qkhid + 8448);
  float* xnh_s = fmisc;                          // 64
  float* svx_s = fmisc + 64;                     // [4][16][4]
  float* mred  = fmisc + 64 + 256;               // [4][64]
  float* c_s   = fmisc + 64 + 256 + 256;         // [4][32]

  // ---- phase 0a: stage c-transform + xnh; compute wvo ----
  if (lane < 32) {
    float rv = rel[(size_t)blockIdx.x*128 + wave*32 + lane];
    float a = log1pf(fabsf(rv));
    c_s[wave*32 + lane] = rv > 0.f ? a : (rv < 0.f ? -a : 0.f);
  }
  if (tid < 64) xnh_s[tid] = xnh[(size_t)blockIdx.x*64 + tid];
  float wvo[4];
  #pragma unroll
  for (int h = 0; h < 4; ++h) {
    float a = 0.f;
    for (int d = 0; d < 16; ++d)
      a = fmaf(v_w[h*16+d], out_w[(size_t)(h*16+d)*64 + lane], a);
    wvo[h] = a;
  }

  // ---- phase 0b-1: hidden (2->128 relu), all 128 ch, plain bf16 ----
  {
    const float w10a = pe_w1[lane],    w11a = pe_w1[128+lane],    b1a = pe_b1[lane];
    const float w10b = pe_w1[64+lane], w11b = pe_w1[192+lane],    b1b = pe_b1[64+lane];
    #pragma unroll
    for (int i = 0; i < 16; ++i) {
      float c0 = c_s[wave*32 + i*2], c1v = c_s[wave*32 + i*2 + 1];
      int row = wave*16 + i;
      hid[row*HID_S + lane]      = f2bf(fmaxf(fmaf(c0, w10a, fmaf(c1v, w11a, b1a)), 0.f));
      hid[row*HID_S + 64 + lane] = f2bf(fmaxf(fmaf(c0, w10b, fmaf(c1v, w11b, b1b)), 0.f));
    }
  }
  __syncthreads();   // S1: xnh_s visible to all; hid written

  // ---- phase 0b-2: pe MFMA (1-term, own 16 rows x all 64 ch) ----
  f32x4 acc_pe[4];
  #pragma unroll
  for (int nf = 0; nf < 4; ++nf) acc_pe[nf] = (f32x4){0,0,0,0};
  #pragma unroll
  for (int ks = 0; ks < 4; ++ks) {
    short8 ah = *(const short8*)&hid[(wave*16+fr)*HID_S + ks*32 + fq*8];
    #pragma unroll
    for (int nf = 0; nf < 4; ++nf) {
      short8 bh = *(const short8*)&pew2t_hi[(nf*16+fr)*128 + ks*32 + fq*8];
      acc_pe[nf] = __builtin_amdgcn_mfma_f32_16x16x32_bf16(ah, bh, acc_pe[nf], 0,0,0);
    }
  }

  // ---- phase 0c: +pe_b2 +xnh, LN1 (16-lane reduce), write h hi/lo ----
  {
    float gv[4], bv[4], b2v[4];
    #pragma unroll
    for (int nf = 0; nf < 4; ++nf) {
      int ch = nf*16 + fr;
      gv[nf] = ln1_g[ch]; bv[nf] = ln1_b[ch]; b2v[nf] = pe_b2[ch];
    }
    #pragma unroll
    for (int r = 0; r < 4; ++r) {
      const int row = wave*16 + fq*4 + r;
      const float xv = xnh_s[row];
      float t[4];
      #pragma unroll
      for (int nf = 0; nf < 4; ++nf) t[nf] = acc_pe[nf][r] + b2v[nf] + xv;
      float ps = t[0]+t[1]+t[2]+t[3];
      #pragma unroll
      for (int off = 1; off < 16; off <<= 1) ps += __shfl_xor(ps, off, 64);
      float mu = ps * (1.f/64.f);
      float vs = 0.f;
      #pragma unroll
      for (int nf = 0; nf < 4; ++nf) { float d = t[nf]-mu; vs = fmaf(d,d,vs); }
      #pragma unroll
      for (int off = 1; off < 16; off <<= 1) vs += __shfl_xor(vs, off, 64);
      float rs = rsqrtf(vs*(1.f/64.f) + 1e-5f);
      #pragma unroll
      for (int nf = 0; nf < 4; ++nf) {
        int ch = nf*16 + fr;
        float hn = (t[nf]-mu)*rs*gv[nf] + bv[nf];
        u16 hh = f2bf(hn);
        h_bf0[row*HBF_S + ch] = hh;
        h_bf1[row*HBF_S + ch] = f2bf(hn - bf2f(hh));
      }
    }
  }
  __syncthreads();   // S2: h_bf complete; hid reads done (q_s may alias)

  // ---- phase 2: q/k MFMA (1-term). wave w: q cols w*16.., k cols 64+w*16.. ----
  {
    short8 bqh[2], bkh[2];
    #pragma unroll
    for (int ks = 0; ks < 2; ++ks) {
      const int qcol = wave*16 + fr, kcol = 64 + wave*16 + fr;
      const int ko = ks*32 + fq*8;
      bqh[ks] = *(const short8*)&qkwt_hi[qcol*64 + ko];
      bkh[ks] = *(const short8*)&qkwt_hi[kcol*64 + ko];
    }
    f32x4 accq[4], acck[4];
    #pragma unroll
    for (int mf = 0; mf < 4; ++mf) { accq[mf] = (f32x4){0,0,0,0}; acck[mf] = (f32x4){0,0,0,0}; }
    #pragma unroll
    for (int ks = 0; ks < 2; ++ks) {
      #pragma unroll
      for (int mf = 0; mf < 4; ++mf) {
        short8 ah = *(const short8*)&h_bf0[(mf*16+fr)*HBF_S + ks*32 + fq*8];
        accq[mf] = __builtin_amdgcn_mfma_f32_16x16x32_bf16(ah, bqh[ks], accq[mf], 0,0,0);
        acck[mf] = __builtin_amdgcn_mfma_f32_16x16x32_bf16(ah, bkh[ks], acck[mf], 0,0,0);
      }
    }
    // private [64][16] panels per wave -> no barrier needed before phase 3
    #pragma unroll
    for (int mf = 0; mf < 4; ++mf)
      #pragma unroll
      for (int r = 0; r < 4; ++r) {
        const int row = mf*16 + fq*4 + r;
        q_sB[(wave*64+row)*QKS3 + fr] = f2bf(accq[mf][r]);
        k_sB[(wave*64+row)*QKS3 + fr] = f2bf(acck[mf][r]);
      }
  }

  // ---- phase 3: attention. lane = block row, head = wave (own panels) ----
  {
    const int nl = lane >> 4, il = lane & 15;
    const float sc = expf(fminf(logit_scale[wave], 4.60517019f));
    float qv[16]; float qs = 0.f;
    short8 qp0 = *(const short8*)&q_sB[(wave*64+lane)*QKS3 + 0];
    short8 qp1 = *(const short8*)&q_sB[(wave*64+lane)*QKS3 + 8];
    #pragma unroll
    for (int d = 0; d < 8; ++d) {
      qv[d]   = bf2f((u16)qp0[d]);  qs = fmaf(qv[d],   qv[d],   qs);
      qv[8+d] = bf2f((u16)qp1[d]);  qs = fmaf(qv[8+d], qv[8+d], qs);
    }
    const float rq = 1.f / (sqrtf(qs) + 1e-12f);
    float lg[16];
    #pragma unroll
    for (int j = 0; j < 16; ++j) {
      const int krow = (lane & 48) + j;
      short8 kp0 = *(const short8*)&k_sB[(wave*64+krow)*QKS3 + 0];
      short8 kp1 = *(const short8*)&k_sB[(wave*64+krow)*QKS3 + 8];
      float ks = 0.f, dt = 0.f;
      #pragma unroll
      for (int d = 0; d < 8; ++d) {
        float kv0 = bf2f((u16)kp0[d]);
        float kv1 = bf2f((u16)kp1[d]);
        ks = fmaf(kv0, kv0, ks); dt = fmaf(qv[d], kv0, dt);
        ks = fmaf(kv1, kv1, ks); dt = fmaf(qv[8+d], kv1, dt);
      }
      lg[j] = dt * rq * (1.f/(sqrtf(ks)+1e-12f)) * sc;
    }
    float mx = lg[0];
    #pragma unroll
    for (int j = 1; j < 16; ++j) mx = fmaxf(mx, lg[j]);
    float se = 0.f, sx = 0.f;
    #pragma unroll
    for (int j = 0; j < 16; ++j) {
      float e = __expf(lg[j] - mx);
      se += e;
      sx = fmaf(e, xnh_s[(lane & 48) + j], sx);
    }
    svx_s[(nl*16 + il)*4 + wave] = sx / se;
  }
  __syncthreads();   // S3: svx cross-wave

  // ---- phase 4: factorized out-proj + residual + LN2 (lane = channel) ----
  const float ob = out_b[lane], g2 = ln2_g[lane], bb2 = ln2_b[lane];
  float h2[16];
  #pragma unroll
  for (int i = 0; i < 16; ++i) {
    float hfull = bf2f(h_bf0[(wave*16+i)*HBF_S + lane])
                + bf2f(h_bf1[(wave*16+i)*HBF_S + lane]);
    float o = ob;
    #pragma unroll
    for (int h = 0; h < 4; ++h) o = fmaf(svx_s[(wave*16+i)*4 + h], wvo[h], o);
    float t = hfull + o;
    float mu = wsum64(t) * (1.f/64.f);
    float d = t - mu;
    float var = wsum64(d*d) * (1.f/64.f);
    h2[i] = d * rsqrtf(var + 1e-5f) * g2 + bb2;
    h_bf0[(wave*16+i)*HBF_S + lane] = f2bf(h2[i]);   // plain bf16 enough for nh path
  }
  __syncthreads();   // S4: h2 cross-wave for phase 5

  // ---- phase 5: nh layer-1 MFMA (1-term) + fused leaky+dot(nh_w2) ----
  {
    short8 bnh[2][2];   // [cf][ks]
    float b1v[2], w2v[2];
    #pragma unroll
    for (int cf = 0; cf < 2; ++cf) {
      const int col = wave*32 + cf*16 + fr;
      b1v[cf] = nh_b1[col];
      w2v[cf] = nh_w2[col];
      #pragma unroll
      for (int ks = 0; ks < 2; ++ks)
        bnh[cf][ks] = *(const short8*)&nhw1t_hi[col*64 + ks*32 + fq*8];
    }
    f32x4 accm[4][2];
    #pragma unroll
    for (int mf = 0; mf < 4; ++mf)
      #pragma unroll
      for (int cf = 0; cf < 2; ++cf) accm[mf][cf] = (f32x4){0,0,0,0};
    #pragma unroll
    for (int ks = 0; ks < 2; ++ks) {
      #pragma unroll
      for (int mf = 0; mf < 4; ++mf) {
        short8 ah = *(const short8*)&h_bf0[(mf*16+fr)*HBF_S + ks*32 + fq*8];
        #pragma unroll
        for (int cf = 0; cf < 2; ++cf)
          accm[mf][cf] = __builtin_amdgcn_mfma_f32_16x16x32_bf16(ah, bnh[cf][ks], accm[mf][cf], 0,0,0);
      }
    }
    #pragma unroll
    for (int mf = 0; mf < 4; ++mf)
      #pragma unroll
      for (int r = 0; r < 4; ++r) {
        float p = leaky_(accm[mf][0][r] + b1v[0]) * w2v[0]
                + leaky_(accm[mf][1][r] + b1v[1]) * w2v[1];
        #pragma unroll
        for (int off = 1; off < 16; off <<= 1) p += __shfl_xor(p, off, 64);
        if (fr == 0) mred[wave*64 + mf*16 + fq*4 + r] = p;
      }
  }
  __syncthreads();   // S5: mred cross-wave

  // ---- phase 6: m broadcast + residual + LN3 -> hu ----
  const float nb2 = nh_b2[0];
  float h3[16];
  float s1 = 0.f, s2 = 0.f;
  #pragma unroll
  for (int i = 0; i < 16; ++i) {
    float sm = mred[0*64 + wave*16+i] + mred[1*64 + wave*16+i]
             + mred[2*64 + wave*16+i] + mred[3*64 + wave*16+i];
    float mi = leaky_(sm + nb2);
    float v3 = h2[i] + mi;
    h3[i] = v3;
    s1 += v3; s2 = fmaf(v3, v3, s2);
  }
  s1 = wsum64(s1); s2 = wsum64(s2);
  float mu = s1 * (1.f/1024.f);
  float var = s2 * (1.f/1024.f) - mu*mu;
  float rs = rsqrtf(var + 1e-5f);
  const size_t base = (size_t)n * 1024;
  #pragma unroll
  for (int i = 0; i < 16; ++i) {
    int cch = i*64 + lane;
    float v = (h3[i] - mu) * rs * ln3_g[cch] + ln3_b[cch];
    u16 hi16 = f2bf(v);
    hu_hi[base + cch] = hi16;
    hu_lo[base + cch] = f2bf(v - bf2f(hi16));
  }
}

// ---------------------------------------------------------------------------
// K0: uf weight split+transpose: W[K][N] fp32 -> Wt_hi/Wt_lo [N][K] bf16.
// ---------------------------------------------------------------------------
__global__ __launch_bounds__(256) void k0_wsplit(
    const float* __restrict__ W1, const float* __restrict__ W2,
    u16* __restrict__ T1h, u16* __restrict__ T1l,
    u16* __restrict__ T2h, u16* __restrict__ T2l) {
  __shared__ float t[64][65];
  const float* W = blockIdx.z ? W2 : W1;
  u16* Th = blockIdx.z ? T2h : T1h;
  u16* Tl = blockIdx.z ? T2l : T1l;
  const int bx = blockIdx.x * 64, by = blockIdx.y * 64;
  for (int i = threadIdx.x; i < 64*64; i += 256) {
    int r = i >> 6, c = i & 63;
    t[r][c] = W[(size_t)(bx + r) * 1024 + by + c];
  }
  __syncthreads();
  for (int i = threadIdx.x; i < 64*64; i += 256) {
    int r2 = i >> 6, c2 = i & 63;
    float v = t[c2][r2];
    u16 hi = f2bf(v);
    size_t o = (size_t)(by + r2) * 1024 + bx + c2;
    Th[o] = hi;
    Tl[o] = f2bf(v - bf2f(hi));
  }
}

// ---------------------------------------------------------------------------
// K0b: small-weight split+transpose for k3's MFMA phases.
// ---------------------------------------------------------------------------
__global__ __launch_bounds__(256) void k0b_wsplit2(
    const float* __restrict__ q_w, const float* __restrict__ k_w,
    const float* __restrict__ nh_w1, const float* __restrict__ pe_w2,
    u16* __restrict__ qkwt_hi, u16* __restrict__ qkwt_lo,
    u16* __restrict__ nhw1t_hi, u16* __restrict__ nhw1t_lo,
    u16* __restrict__ pew2t_hi, u16* __restrict__ pew2t_lo) {
  int idx = blockIdx.x * 256 + threadIdx.x;   // 0 .. 24575
  if (idx < 8192) {
    int col = idx >> 6, kk = idx & 63;
    float v = (col < 64) ? q_w[kk*64 + col] : k_w[kk*64 + (col - 64)];
    u16 hi = f2bf(v);
    qkwt_hi[col*64 + kk] = hi;
    qkwt_lo[col*64 + kk] = f2bf(v - bf2f(hi));
  } else if (idx < 16384) {
    int e = idx - 8192;
    int col = e >> 6, kk = e & 63;
    float v = nh_w1[kk*128 + col];
    u16 hi = f2bf(v);
    nhw1t_hi[col*64 + kk] = hi;
    nhw1t_lo[col*64 + kk] = f2bf(v - bf2f(hi));
  } else {
    int e = idx - 16384;
    int col = e >> 7, j = e & 127;
    float v = pe_w2[j*64 + col];
    u16 hi = f2bf(v);
    pew2t_hi[col*128 + j] = hi;
    pew2t_lo[col*128 + j] = f2bf(v - bf2f(hi));
  }
}

// ---------------------------------------------------------------------------
// K5: split-bf16 MFMA GEMM (verified) + XCD-aware block swizzle.
// ---------------------------------------------------------------------------
template<int OUT_BF16>
__global__ __launch_bounds__(256, 2) void k5_gemm(
    const u16* __restrict__ Ah, const u16* __restrict__ Al,
    const u16* __restrict__ Bth, const u16* __restrict__ Btl,
    const float* __restrict__ bias,
    u16* __restrict__ Chi, u16* __restrict__ Clo, float* __restrict__ Cf) {
  __shared__ u16 As[2][128*32];
  __shared__ u16 Bs[2][128*32];
  const int tid = threadIdx.x;
  const int lane = tid & 63;
  const int wave = tid >> 6;
  const int wr = (wave >> 1) * 64, wc = (wave & 1) * 64;
  const int bid = (int)blockIdx.x;
  const int swz = (bid & 7) * 64 + (bid >> 3);
  const int mt = swz >> 3, nt = swz & 7;
  const int m0 = mt * 128, n0 = nt * 128;

  const int sr = tid >> 2, sk = (tid & 3) * 8;
  const size_t a_off = (size_t)(m0 + sr) * 1024 + sk;
  const size_t b_off = (size_t)(n0 + sr) * 1024 + sk;
  u16* lAh = &As[0][0] + tid * 8;
  u16* lAl = &As[1][0] + tid * 8;
  u16* lBh = &Bs[0][0] + tid * 8;
  u16* lBl = &Bs[1][0] + tid * 8;

  f32x4 acc[4][4];
  #pragma unroll
  for (int i = 0; i < 4; ++i)
    #pragma unroll
    for (int j = 0; j < 4; ++j) acc[i][j] = (f32x4){0.f, 0.f, 0.f, 0.f};

  const int fr = lane & 15, fq = lane >> 4;
  const int aoff = (wr + fr) * 32 + fq * 8;
  const int boff = (wc + fr) * 32 + fq * 8;

  for (int k0 = 0; k0 < 1024; k0 += 32) {
    __syncthreads();
    gload16(Ah  + a_off + k0,             lAh);
    gload16(Ah  + a_off + k0 + 64*1024,   lAh + 64*32);
    gload16(Al  + a_off + k0,             lAl);
    gload16(Al  + a_off + k0 + 64*1024,   lAl + 64*32);
    gload16(Bth + b_off + k0,             lBh);
    gload16(Bth + b_off + k0 + 64*1024,   lBh + 64*32);
    gload16(Btl + b_off + k0,             lBl);
    gload16(Btl + b_off + k0 + 64*1024,   lBl + 64*32);
    __syncthreads();

    short8 ah[4], al[4], bh[4], bl[4];
    #pragma unroll
    for (int i = 0; i < 4; ++i) {
      ah[i] = *(const short8*)&As[0][aoff + i*16*32];
      al[i] = *(const short8*)&As[1][aoff + i*16*32];
      bh[i] = *(const short8*)&Bs[0][boff + i*16*32];
      bl[i] = *(const short8*)&Bs[1][boff + i*16*32];
    }
    #pragma unroll
    for (int mi = 0; mi < 4; ++mi)
      #pragma unroll
      for (int ni = 0; ni < 4; ++ni) {
        acc[mi][ni] = __builtin_amdgcn_mfma_f32_16x16x32_bf16(ah[mi], bh[ni], acc[mi][ni], 0, 0, 0);
        acc[mi][ni] = __builtin_amdgcn_mfma_f32_16x16x32_bf16(ah[mi], bl[ni], acc[mi][ni], 0, 0, 0);
        acc[mi][ni] = __builtin_amdgcn_mfma_f32_16x16x32_bf16(al[mi], bh[ni], acc[mi][ni], 0, 0, 0);
      }
  }

  #pragma unroll
  for (int mi = 0; mi < 4; ++mi)
    #pragma unroll
    for (int ni = 0; ni < 4; ++ni) {
      const int col = n0 + wc + ni*16 + fr;
      const float bv = bias[col];
      #pragma unroll
      for (int r = 0; r < 4; ++r) {
        const int row = m0 + wr + mi*16 + fq*4 + r;
        float v = leaky_(acc[mi][ni][r] + bv);
        if (OUT_BF16) {
          u16 hi = f2bf(v);
          Chi[(size_t)row*1024 + col] = hi;
          Clo[(size_t)row*1024 + col] = f2bf(v - bf2f(hi));
        } else {
          Cf[(size_t)row*1024 + col] = v;
        }
      }
    }
}

// ---------------------------------------------------------------------------
extern "C" void kernel_launch(void* const* d_in, const int* in_sizes, int n_in,
                              void* d_out, int out_size, void* d_ws, size_t ws_size,
                              hipStream_t stream) {
  (void)in_sizes; (void)n_in; (void)out_size; (void)ws_size;
  const float* x     = (const float*)d_in[0];
  const float* ct    = (const float*)d_in[1];
  const float* cs    = (const float*)d_in[2];
  const float* pe_w1 = (const float*)d_in[3];
  const float* pe_b1 = (const float*)d_in[4];
  const float* pe_w2 = (const float*)d_in[5];
  const float* pe_b2 = (const float*)d_in[6];
  const float* q_w   = (const float*)d_in[7];
  const float* k_w   = (const float*)d_in[8];
  const float* v_w   = (const float*)d_in[9];
  const float* lsc   = (const float*)d_in[10];
  const float* out_w = (const float*)d_in[11];
  const float* out_b = (const float*)d_in[12];
  const float* nh_w1 = (const float*)d_in[13];
  const float* nh_b1 = (const float*)d_in[14];
  const float* nh_w2 = (const float*)d_in[15];
  const float* nh_b2 = (const float*)d_in[16];
  const float* uf_w1 = (const float*)d_in[17];
  const float* uf_b1 = (const float*)d_in[18];
  const float* uf_w2 = (const float*)d_in[19];
  const float* uf_b2 = (const float*)d_in[20];
  const float* ln1_g = (const float*)d_in[21];
  const float* ln1_b = (const float*)d_in[22];
  const float* ln2_g = (const float*)d_in[23];
  const float* ln2_b = (const float*)d_in[24];
  const float* ln3_g = (const float*)d_in[25];
  const float* ln3_b = (const float*)d_in[26];

  float* ws  = (float*)d_ws;
  float* xnh = ws;                                  // 131072 f
  float* rel = ws + 131072;                         // 262144 f
  float* h   = ws + 393216;                         // 8388608 f (mid hi/lo alias)
  u16*  hu_hi = (u16*)(ws + 393216 + 8388608);      // 8388608 u16
  u16*  hu_lo = hu_hi + 8388608;                    // 8388608 u16
  u16*  wbase = (u16*)(ws + 393216 + 2*8388608);
  u16*  w1t_hi = wbase;                             // 1048576 u16 each
  u16*  w1t_lo = wbase + 1048576;
  u16*  w2t_hi = wbase + 2*1048576;
  u16*  w2t_lo = wbase + 3*1048576;
  u16*  qkwt_hi  = wbase + 4*1048576;               // 8192 u16 each
  u16*  qkwt_lo  = qkwt_hi + 8192;
  u16*  nhw1t_hi = qkwt_hi + 16384;
  u16*  nhw1t_lo = qkwt_hi + 24576;
  u16*  pew2t_hi = qkwt_hi + 32768;
  u16*  pew2t_lo = qkwt_hi + 40960;
  u16*  mid_hi = (u16*)h;
  u16*  mid_lo = mid_hi + 8388608;
  float* out = (float*)d_out;

  k0_wsplit<<<dim3(16, 16, 2), dim3(256), 0, stream>>>(uf_w1, uf_w2,
                                                       w1t_hi, w1t_lo, w2t_hi, w2t_lo);
  k0b_wsplit2<<<dim3(96), dim3(256), 0, stream>>>(q_w, k_w, nh_w1, pe_w2,
                                                  qkwt_hi, qkwt_lo, nhw1t_hi, nhw1t_lo,
                                                  pew2t_hi, pew2t_lo);
  k1_knn<<<dim3(BT_/4), dim3(256), 0, stream>>>(ct, cs, x, xnh, rel);
  k3_attn<<<dim3(BT_/4), dim3(256), 0, stream>>>(rel, xnh, pe_w1, pe_b1,
                                                 pew2t_hi, pew2t_lo, pe_b2,
                                                 ln1_g, ln1_b,
                                                 qkwt_hi, qkwt_lo, nhw1t_hi, nhw1t_lo,
                                                 v_w, lsc, out_w, out_b,
                                                 nh_b1, nh_w2, nh_b2,
                                                 ln2_g, ln2_b, ln3_g, ln3_b, hu_hi, hu_lo);
  k5_gemm<1><<<dim3(512), dim3(256), 0, stream>>>(hu_hi, hu_lo, w1t_hi, w1t_lo, uf_b1,
                                                  mid_hi, mid_lo, nullptr);
  k5_gemm<0><<<dim3(512), dim3(256), 0, stream>>>(mid_hi, mid_lo, w2t_hi, w2t_lo, uf_b2,
                                                  nullptr, nullptr, out);
}